// Round 3
// baseline (2321.105 us; speedup 1.0000x reference)
//
#include <hip/hip_runtime.h>
#include <hip/hip_bf16.h>
#include <math.h>

// Problem constants (fixed by the reference)
#define N_NODES 50000
#define N_EDGES 800000
#define NODE_DIM 3
#define EDGE_DIM 32
#define HIDDEN 128
#define NUM_GRAPHS 256
#define ZIN (2*HIDDEN + EDGE_DIM)   // 288

// ---------------------------------------------------------------------------
// conv1: CGConv on 3-dim features. One thread per edge.
// ---------------------------------------------------------------------------
__global__ __launch_bounds__(256) void conv1_kernel(
    const float* __restrict__ x, const int* __restrict__ ei,
    const float* __restrict__ EA,
    const float* __restrict__ Wf1, const float* __restrict__ bf1,
    const float* __restrict__ Ws1, const float* __restrict__ bs1,
    float* __restrict__ agg0)
{
    __shared__ float WfL[38*3], WsL[38*3], bfL[3], bsL[3];
    if (threadIdx.x < 114) {
        WfL[threadIdx.x] = Wf1[threadIdx.x];
        WsL[threadIdx.x] = Ws1[threadIdx.x];
    }
    if (threadIdx.x < 3) { bfL[threadIdx.x] = bf1[threadIdx.x]; bsL[threadIdx.x] = bs1[threadIdx.x]; }
    __syncthreads();

    int e = blockIdx.x * 256 + threadIdx.x;
    if (e >= N_EDGES) return;
    int s = ei[e];
    int d = ei[N_EDGES + e];

    float z[38];
    z[0] = x[d*3+0]; z[1] = x[d*3+1]; z[2] = x[d*3+2];
    z[3] = x[s*3+0]; z[4] = x[s*3+1]; z[5] = x[s*3+2];
    const float4* ep = (const float4*)(EA + (size_t)e * EDGE_DIM);
    #pragma unroll
    for (int q = 0; q < 8; ++q) {
        float4 v = ep[q];
        z[6+4*q+0] = v.x; z[6+4*q+1] = v.y; z[6+4*q+2] = v.z; z[6+4*q+3] = v.w;
    }
    float f[3], g[3];
    #pragma unroll
    for (int c = 0; c < 3; ++c) { f[c] = bfL[c]; g[c] = bsL[c]; }
    #pragma unroll
    for (int j = 0; j < 38; ++j) {
        #pragma unroll
        for (int c = 0; c < 3; ++c) {
            f[c] += z[j] * WfL[j*3+c];
            g[c] += z[j] * WsL[j*3+c];
        }
    }
    #pragma unroll
    for (int c = 0; c < 3; ++c) {
        float sig = __builtin_amdgcn_rcpf(1.0f + __expf(-f[c]));
        float sp  = fmaxf(g[c], 0.0f) + __logf(1.0f + __expf(-fabsf(g[c])));
        atomicAdd(agg0 + (size_t)d*3 + c, sig * sp);
    }
}

// ---------------------------------------------------------------------------
// proj: H[n][c] = relu(bp[c] + sum_j (x[n][j]+agg0[n][j]) * Wp[j][c])
// ---------------------------------------------------------------------------
__global__ __launch_bounds__(256) void proj_kernel(
    const float* __restrict__ x, const float* __restrict__ agg0,
    const float* __restrict__ Wp, const float* __restrict__ bp,
    float* __restrict__ H)
{
    int idx = blockIdx.x * 256 + threadIdx.x;
    if (idx >= N_NODES * HIDDEN) return;
    int n = idx >> 7, c = idx & 127;
    float h0 = x[n*3+0] + agg0[n*3+0];
    float h1 = x[n*3+1] + agg0[n*3+1];
    float h2 = x[n*3+2] + agg0[n*3+2];
    float v = bp[c] + h0*Wp[0*128+c] + h1*Wp[1*128+c] + h2*Wp[2*128+c];
    H[idx] = fmaxf(v, 0.0f);
}

// ---------------------------------------------------------------------------
// Repack layer weights into Wcat (128 x 512), INTERLEAVED column layout:
//   n in [0,256):   n = 2c+t  -> t=0: Wf[k][c] (dst rows), t=1: Ws[k][c]
//   n in [256,512): n-256=2c+t-> t=0: Wf[128+k][c] (src),  t=1: Ws[128+k][c]
// So P[n][2c],P[n][2c+1] = (f_dst,s_dst) and P[n][256+2c..] = (f_src,s_src):
// the edge kernel fetches each node's contribution as ONE float2.
// ---------------------------------------------------------------------------
__global__ __launch_bounds__(256) void repack_kernel(
    const float* __restrict__ Wf, const float* __restrict__ Ws,
    float* __restrict__ Wcat)
{
    int idx = blockIdx.x * 256 + threadIdx.x;   // 2 * 128 * 512 total
    if (idx >= 2*128*512) return;
    int l = idx >> 16;
    int rem = idx & 65535;
    int k = rem >> 9, n = rem & 511;
    const float* wf = Wf + (size_t)l * ZIN * HIDDEN;
    const float* wsp = Ws + (size_t)l * ZIN * HIDDEN;
    int half = n >> 8;          // 0 = dst rows, 1 = src rows
    int within = n & 255;
    int cc = within >> 1;
    int t = within & 1;         // 0 = Wf, 1 = Ws
    const float* W = t ? wsp : wf;
    Wcat[idx] = W[(size_t)(half*128 + k)*128 + cc];
}

// ---------------------------------------------------------------------------
// GEMM: C(MxN) = A(MxK) @ B(KxN), fp32, 64x64 tile, 4x4 per thread, k-step 16
// ---------------------------------------------------------------------------
__global__ __launch_bounds__(256) void gemm64(
    const float* __restrict__ A, const float* __restrict__ B,
    float* __restrict__ C, int M, int N, int K)
{
    __shared__ float As[16][65];
    __shared__ float Bs[16][65];
    const int tid = threadIdx.x;
    const int tx = tid & 15;
    const int ty = tid >> 4;
    const int colBase = blockIdx.x * 64;
    const int rowBase = blockIdx.y * 64;
    const int am = tid >> 2;          // 0..63
    const int ak = (tid & 3) * 4;     // 0,4,8,12
    const int bk = tid >> 4;          // 0..15
    const int bn = (tid & 15) * 4;

    float acc[4][4];
    #pragma unroll
    for (int i = 0; i < 4; ++i)
        #pragma unroll
        for (int j = 0; j < 4; ++j) acc[i][j] = 0.0f;

    for (int k0 = 0; k0 < K; k0 += 16) {
        int arow = rowBase + am;
        float4 a4 = make_float4(0.f, 0.f, 0.f, 0.f);
        if (arow < M) a4 = *(const float4*)(A + (size_t)arow * K + k0 + ak);
        float4 b4 = *(const float4*)(B + (size_t)(k0 + bk) * N + colBase + bn);
        __syncthreads();
        As[ak+0][am] = a4.x; As[ak+1][am] = a4.y; As[ak+2][am] = a4.z; As[ak+3][am] = a4.w;
        Bs[bk][bn+0] = b4.x; Bs[bk][bn+1] = b4.y; Bs[bk][bn+2] = b4.z; Bs[bk][bn+3] = b4.w;
        __syncthreads();
        #pragma unroll
        for (int k = 0; k < 16; ++k) {
            float a0 = As[k][ty*4+0], a1 = As[k][ty*4+1], a2 = As[k][ty*4+2], a3 = As[k][ty*4+3];
            float b0 = Bs[k][tx*4+0], b1 = Bs[k][tx*4+1], b2 = Bs[k][tx*4+2], b3 = Bs[k][tx*4+3];
            acc[0][0] += a0*b0; acc[0][1] += a0*b1; acc[0][2] += a0*b2; acc[0][3] += a0*b3;
            acc[1][0] += a1*b0; acc[1][1] += a1*b1; acc[1][2] += a1*b2; acc[1][3] += a1*b3;
            acc[2][0] += a2*b0; acc[2][1] += a2*b1; acc[2][2] += a2*b2; acc[2][3] += a2*b3;
            acc[3][0] += a3*b0; acc[3][1] += a3*b1; acc[3][2] += a3*b2; acc[3][3] += a3*b3;
        }
    }
    #pragma unroll
    for (int i = 0; i < 4; ++i) {
        int r = rowBase + ty*4 + i;
        if (r >= M) continue;
        #pragma unroll
        for (int j = 0; j < 4; ++j) {
            C[(size_t)r * N + colBase + tx*4 + j] = acc[i][j];
        }
    }
}

// ---------------------------------------------------------------------------
// Fused edge kernel, v3.
// 128 threads per edge; 64 weight values per lane HARD-PINNED in VGPRs via
// empty inline-asm (defeats LLVM's invariant-load rematerialization, which
// made v2 L1-BW-bound at ~26 GB/layer of weight refetch).
// __launch_bounds__(256,3): ~170 VGPR budget, 12 waves/CU.
// P is interleaved: one float2 per node fetches (f,s) contributions.
// ---------------------------------------------------------------------------
__global__ __launch_bounds__(256, 3) void edge_kernel(
    const float* __restrict__ P, const float* __restrict__ EA,
    const int* __restrict__ ei,
    const float* __restrict__ Wfe, const float* __restrict__ Wse,  // (32,128) each
    const float* __restrict__ bf, const float* __restrict__ bs,
    float* __restrict__ agg)
{
    const int c = threadIdx.x & 127;
    const int sub = threadIdx.x >> 7;
    float wf[32], ws[32];
    #pragma unroll
    for (int k = 0; k < 32; ++k) { wf[k] = Wfe[k*128 + c]; ws[k] = Wse[k*128 + c]; }
    // Pin all 64 weight values in VGPRs: an asm result can't be rematerialized.
    #pragma unroll
    for (int k = 0; k < 32; ++k) {
        asm volatile("" : "+v"(wf[k]), "+v"(ws[k]));
    }
    const float bfc = bf[c], bsc = bs[c];
    const int stride = gridDim.x * 2;
    const int* srcA = ei;
    const int* dstA = ei + N_EDGES;

    for (int e = blockIdx.x * 2 + sub; e < N_EDGES; e += stride) {
        int s = srcA[e];
        int d = dstA[e];
        const float4* ep = (const float4*)(EA + (size_t)e * EDGE_DIM);
        // independent accumulators: edge-dot proceeds while P gathers fly
        float fd = 0.0f, gd = 0.0f;
        #pragma unroll
        for (int q = 0; q < 8; ++q) {
            float4 v = ep[q];
            fd += v.x*wf[4*q+0] + v.y*wf[4*q+1] + v.z*wf[4*q+2] + v.w*wf[4*q+3];
            gd += v.x*ws[4*q+0] + v.y*ws[4*q+1] + v.z*ws[4*q+2] + v.w*ws[4*q+3];
        }
        float2 vd = *(const float2*)(P + (size_t)d * 512 + 2*c);
        float2 vs = *(const float2*)(P + (size_t)s * 512 + 256 + 2*c);
        float f = bfc + vd.x + vs.x + fd;
        float g = bsc + vd.y + vs.y + gd;
        float sig = __builtin_amdgcn_rcpf(1.0f + __expf(-f));
        float sp  = fmaxf(g, 0.0f) + __logf(1.0f + __expf(-fabsf(g)));
        atomicAdd(agg + (size_t)d * HIDDEN + c, sig * sp);
    }
}

// ---------------------------------------------------------------------------
// H = relu(H + agg)
// ---------------------------------------------------------------------------
__global__ __launch_bounds__(256) void update_kernel(
    float* __restrict__ H, const float* __restrict__ agg)
{
    int idx = blockIdx.x * 256 + threadIdx.x;
    if (idx >= N_NODES * HIDDEN) return;
    H[idx] = fmaxf(H[idx] + agg[idx], 0.0f);
}

// ---------------------------------------------------------------------------
// Pool: per-graph sums + counts (batch sorted; run-length then atomic).
// ---------------------------------------------------------------------------
__global__ __launch_bounds__(128) void pool_kernel(
    const float* __restrict__ H, const int* __restrict__ batch,
    float* __restrict__ gsum, float* __restrict__ gcnt)
{
    const int c = threadIdx.x;
    const int n0 = blockIdx.x * 128;
    float acc = 0.0f;
    int cur = -1;
    for (int i = 0; i < 128; ++i) {
        int n = n0 + i;
        if (n >= N_NODES) break;
        int g = batch[n];
        if (g != cur) {
            if (cur >= 0) atomicAdd(gsum + (size_t)cur * HIDDEN + c, acc);
            cur = g; acc = 0.0f;
        }
        acc += H[(size_t)n * HIDDEN + c];
    }
    if (cur >= 0) atomicAdd(gsum + (size_t)cur * HIDDEN + c, acc);

    if (c == 0) {
        int curg = -1; float run = 0.0f;
        for (int i = 0; i < 128; ++i) {
            int n = n0 + i;
            if (n >= N_NODES) break;
            int g = batch[n];
            if (g != curg) {
                if (curg >= 0) atomicAdd(gcnt + curg, run);
                curg = g; run = 0.0f;
            }
            run += 1.0f;
        }
        if (curg >= 0) atomicAdd(gcnt + curg, run);
    }
}

// ---------------------------------------------------------------------------
// Final MLP: g = relu((gsum/cnt) @ W1 + b1); out = g @ Wh^T + bh
// ---------------------------------------------------------------------------
__global__ __launch_bounds__(128) void head_kernel(
    const float* __restrict__ gsum, const float* __restrict__ gcnt,
    const float* __restrict__ W1, const float* __restrict__ b1,
    const float* __restrict__ Wh, const float* __restrict__ bh,
    float* __restrict__ out)
{
    __shared__ float gavg[128];
    __shared__ float g1[128];
    const int g = blockIdx.x, c = threadIdx.x;
    float cnt = fmaxf(gcnt[g], 1.0f);
    gavg[c] = gsum[(size_t)g * HIDDEN + c] / cnt;
    __syncthreads();
    float acc = b1[c];
    for (int k = 0; k < 128; ++k) acc += gavg[k] * W1[k*128 + c];
    g1[c] = fmaxf(acc, 0.0f);
    __syncthreads();
    if (c < 5) {
        float o = bh[c];
        for (int k = 0; k < 128; ++k) o += g1[k] * Wh[c*128 + k];
        out[(size_t)g * 5 + c] = o;
    }
}

// ---------------------------------------------------------------------------
// Launch
// ---------------------------------------------------------------------------
extern "C" void kernel_launch(void* const* d_in, const int* in_sizes, int n_in,
                              void* d_out, int out_size, void* d_ws, size_t ws_size,
                              hipStream_t stream) {
    const float* x        = (const float*)d_in[0];
    const int*   ei       = (const int*)  d_in[1];
    const float* EA       = (const float*)d_in[2];
    const int*   batch    = (const int*)  d_in[3];
    const float* Wf1      = (const float*)d_in[4];
    const float* bf1      = (const float*)d_in[5];
    const float* Ws1      = (const float*)d_in[6];
    const float* bs1      = (const float*)d_in[7];
    const float* Wp       = (const float*)d_in[8];
    const float* bp       = (const float*)d_in[9];
    const float* Wf_convs = (const float*)d_in[10];
    const float* bf_convs = (const float*)d_in[11];
    const float* Ws_convs = (const float*)d_in[12];
    const float* bs_convs = (const float*)d_in[13];
    const float* W1       = (const float*)d_in[14];
    const float* b1       = (const float*)d_in[15];
    const float* W_heads  = (const float*)d_in[16];
    const float* b_heads  = (const float*)d_in[17];
    float* out = (float*)d_out;

    float* ws = (float*)d_ws;
    // workspace layout (floats), offsets 64-aligned
    float* agg0 = ws + 0;                       // 150000
    float* H    = ws + 150016;                  // 6,400,000
    float* P    = ws + 6550016;                 // 25,600,000
    float* agg  = ws + 32150016;                // 6,400,000
    float* Wcat = ws + 38550016;                // 131072 (2 layers x 128 x 512)
    float* gsum = ws + 38681088;                // 32768
    float* gcnt = ws + 38713856;                // 256

    // conv1
    hipMemsetAsync(agg0, 0, (size_t)N_NODES * 3 * sizeof(float), stream);
    conv1_kernel<<<(N_EDGES + 255)/256, 256, 0, stream>>>(x, ei, EA, Wf1, bf1, Ws1, bs1, agg0);
    // proj
    proj_kernel<<<(N_NODES*HIDDEN + 255)/256, 256, 0, stream>>>(x, agg0, Wp, bp, H);
    // repack weights for both layers
    repack_kernel<<<(2*128*512 + 255)/256, 256, 0, stream>>>(Wf_convs, Ws_convs, Wcat);

    for (int l = 0; l < 2; ++l) {
        const float* Wcat_l = Wcat + (size_t)l * 128 * 512;
        const float* Wfe = Wf_convs + (size_t)l * ZIN * HIDDEN + 256*128;
        const float* Wse = Ws_convs + (size_t)l * ZIN * HIDDEN + 256*128;
        const float* bfl = bf_convs + (size_t)l * HIDDEN;
        const float* bsl = bs_convs + (size_t)l * HIDDEN;
        // P = H @ Wcat_l  (50000 x 128 x 512)
        dim3 ggrid(512/64, (N_NODES + 63)/64);
        gemm64<<<ggrid, 256, 0, stream>>>(H, Wcat_l, P, N_NODES, 512, 128);
        // agg = 0; edge messages
        hipMemsetAsync(agg, 0, (size_t)N_NODES * HIDDEN * sizeof(float), stream);
        edge_kernel<<<2048, 256, 0, stream>>>(P, EA, ei, Wfe, Wse, bfl, bsl, agg);
        // H = relu(H + agg)
        update_kernel<<<(N_NODES*HIDDEN + 255)/256, 256, 0, stream>>>(H, agg);
    }

    // pool + heads
    hipMemsetAsync(gsum, 0, (size_t)(NUM_GRAPHS * HIDDEN + NUM_GRAPHS) * sizeof(float), stream);
    pool_kernel<<<(N_NODES + 127)/128, 128, 0, stream>>>(H, batch, gsum, gcnt);
    head_kernel<<<NUM_GRAPHS, 128, 0, stream>>>(gsum, gcnt, W1, b1, W_heads, b_heads, out);
}

// Round 4
// 1491.440 us; speedup vs baseline: 1.5563x; 1.5563x over previous
//
#include <hip/hip_runtime.h>
#include <hip/hip_bf16.h>
#include <math.h>

// Problem constants (fixed by the reference)
#define N_NODES 50000
#define N_EDGES 800000
#define NODE_DIM 3
#define EDGE_DIM 32
#define HIDDEN 128
#define NUM_GRAPHS 256
#define ZIN (2*HIDDEN + EDGE_DIM)   // 288

// ---------------------------------------------------------------------------
// conv1: CGConv on 3-dim features. One thread per edge.
// ---------------------------------------------------------------------------
__global__ __launch_bounds__(256) void conv1_kernel(
    const float* __restrict__ x, const int* __restrict__ ei,
    const float* __restrict__ EA,
    const float* __restrict__ Wf1, const float* __restrict__ bf1,
    const float* __restrict__ Ws1, const float* __restrict__ bs1,
    float* __restrict__ agg0)
{
    __shared__ float WfL[38*3], WsL[38*3], bfL[3], bsL[3];
    if (threadIdx.x < 114) {
        WfL[threadIdx.x] = Wf1[threadIdx.x];
        WsL[threadIdx.x] = Ws1[threadIdx.x];
    }
    if (threadIdx.x < 3) { bfL[threadIdx.x] = bf1[threadIdx.x]; bsL[threadIdx.x] = bs1[threadIdx.x]; }
    __syncthreads();

    int e = blockIdx.x * 256 + threadIdx.x;
    if (e >= N_EDGES) return;
    int s = ei[e];
    int d = ei[N_EDGES + e];

    float z[38];
    z[0] = x[d*3+0]; z[1] = x[d*3+1]; z[2] = x[d*3+2];
    z[3] = x[s*3+0]; z[4] = x[s*3+1]; z[5] = x[s*3+2];
    const float4* ep = (const float4*)(EA + (size_t)e * EDGE_DIM);
    #pragma unroll
    for (int q = 0; q < 8; ++q) {
        float4 v = ep[q];
        z[6+4*q+0] = v.x; z[6+4*q+1] = v.y; z[6+4*q+2] = v.z; z[6+4*q+3] = v.w;
    }
    float f[3], g[3];
    #pragma unroll
    for (int c = 0; c < 3; ++c) { f[c] = bfL[c]; g[c] = bsL[c]; }
    #pragma unroll
    for (int j = 0; j < 38; ++j) {
        #pragma unroll
        for (int c = 0; c < 3; ++c) {
            f[c] += z[j] * WfL[j*3+c];
            g[c] += z[j] * WsL[j*3+c];
        }
    }
    #pragma unroll
    for (int c = 0; c < 3; ++c) {
        float sig = __builtin_amdgcn_rcpf(1.0f + __expf(-f[c]));
        float sp  = fmaxf(g[c], 0.0f) + __logf(1.0f + __expf(-fabsf(g[c])));
        atomicAdd(agg0 + (size_t)d*3 + c, sig * sp);
    }
}

// ---------------------------------------------------------------------------
// proj: H[n][c] = relu(bp[c] + sum_j (x[n][j]+agg0[n][j]) * Wp[j][c])
// ---------------------------------------------------------------------------
__global__ __launch_bounds__(256) void proj_kernel(
    const float* __restrict__ x, const float* __restrict__ agg0,
    const float* __restrict__ Wp, const float* __restrict__ bp,
    float* __restrict__ H)
{
    int idx = blockIdx.x * 256 + threadIdx.x;
    if (idx >= N_NODES * HIDDEN) return;
    int n = idx >> 7, c = idx & 127;
    float h0 = x[n*3+0] + agg0[n*3+0];
    float h1 = x[n*3+1] + agg0[n*3+1];
    float h2 = x[n*3+2] + agg0[n*3+2];
    float v = bp[c] + h0*Wp[0*128+c] + h1*Wp[1*128+c] + h2*Wp[2*128+c];
    H[idx] = fmaxf(v, 0.0f);
}

// ---------------------------------------------------------------------------
// Repack layer weights into Wcat (128 x 512), INTERLEAVED column layout:
//   n in [0,256):   n = 2c+t  -> t=0: Wf[k][c] (dst rows), t=1: Ws[k][c]
//   n in [256,512): n-256=2c+t-> t=0: Wf[128+k][c] (src),  t=1: Ws[128+k][c]
// So P[n][2c],P[n][2c+1] = (f_dst,s_dst) and P[n][256+2c..] = (f_src,s_src).
// ---------------------------------------------------------------------------
__global__ __launch_bounds__(256) void repack_kernel(
    const float* __restrict__ Wf, const float* __restrict__ Ws,
    float* __restrict__ Wcat)
{
    int idx = blockIdx.x * 256 + threadIdx.x;   // 2 * 128 * 512 total
    if (idx >= 2*128*512) return;
    int l = idx >> 16;
    int rem = idx & 65535;
    int k = rem >> 9, n = rem & 511;
    const float* wf = Wf + (size_t)l * ZIN * HIDDEN;
    const float* wsp = Ws + (size_t)l * ZIN * HIDDEN;
    int half = n >> 8;          // 0 = dst rows, 1 = src rows
    int within = n & 255;
    int cc = within >> 1;
    int t = within & 1;         // 0 = Wf, 1 = Ws
    const float* W = t ? wsp : wf;
    Wcat[idx] = W[(size_t)(half*128 + k)*128 + cc];
}

// ---------------------------------------------------------------------------
// GEMM: C(MxN) = A(MxK) @ B(KxN), fp32, 64x64 tile, 4x4 per thread, k-step 16
// ---------------------------------------------------------------------------
__global__ __launch_bounds__(256) void gemm64(
    const float* __restrict__ A, const float* __restrict__ B,
    float* __restrict__ C, int M, int N, int K)
{
    __shared__ float As[16][65];
    __shared__ float Bs[16][65];
    const int tid = threadIdx.x;
    const int tx = tid & 15;
    const int ty = tid >> 4;
    const int colBase = blockIdx.x * 64;
    const int rowBase = blockIdx.y * 64;
    const int am = tid >> 2;          // 0..63
    const int ak = (tid & 3) * 4;     // 0,4,8,12
    const int bk = tid >> 4;          // 0..15
    const int bn = (tid & 15) * 4;

    float acc[4][4];
    #pragma unroll
    for (int i = 0; i < 4; ++i)
        #pragma unroll
        for (int j = 0; j < 4; ++j) acc[i][j] = 0.0f;

    for (int k0 = 0; k0 < K; k0 += 16) {
        int arow = rowBase + am;
        float4 a4 = make_float4(0.f, 0.f, 0.f, 0.f);
        if (arow < M) a4 = *(const float4*)(A + (size_t)arow * K + k0 + ak);
        float4 b4 = *(const float4*)(B + (size_t)(k0 + bk) * N + colBase + bn);
        __syncthreads();
        As[ak+0][am] = a4.x; As[ak+1][am] = a4.y; As[ak+2][am] = a4.z; As[ak+3][am] = a4.w;
        Bs[bk][bn+0] = b4.x; Bs[bk][bn+1] = b4.y; Bs[bk][bn+2] = b4.z; Bs[bk][bn+3] = b4.w;
        __syncthreads();
        #pragma unroll
        for (int k = 0; k < 16; ++k) {
            float a0 = As[k][ty*4+0], a1 = As[k][ty*4+1], a2 = As[k][ty*4+2], a3 = As[k][ty*4+3];
            float b0 = Bs[k][tx*4+0], b1 = Bs[k][tx*4+1], b2 = Bs[k][tx*4+2], b3 = Bs[k][tx*4+3];
            acc[0][0] += a0*b0; acc[0][1] += a0*b1; acc[0][2] += a0*b2; acc[0][3] += a0*b3;
            acc[1][0] += a1*b0; acc[1][1] += a1*b1; acc[1][2] += a1*b2; acc[1][3] += a1*b3;
            acc[2][0] += a2*b0; acc[2][1] += a2*b1; acc[2][2] += a2*b2; acc[2][3] += a2*b3;
            acc[3][0] += a3*b0; acc[3][1] += a3*b1; acc[3][2] += a3*b2; acc[3][3] += a3*b3;
        }
    }
    #pragma unroll
    for (int i = 0; i < 4; ++i) {
        int r = rowBase + ty*4 + i;
        if (r >= M) continue;
        #pragma unroll
        for (int j = 0; j < 4; ++j) {
            C[(size_t)r * N + colBase + tx*4 + j] = acc[i][j];
        }
    }
}

// ---------------------------------------------------------------------------
// Fused edge kernel, v4.
// Weight residency strategy (R2 was L1-BW-bound on remat; R3's asm pin caused
// scratch spills):
//  - Weights staged global->LDS, then copied LDS->registers. LDS loads carry
//    no !invariant metadata so LLVM CANNOT rematerialize them.
//  - Occupancy is LDS-capped: 52 KB/block -> 3 blocks/CU = 3 waves/EU, equal
//    to __launch_bounds__(256,3)'s 170-VGPR budget -> no incentive to spill.
//  - e/src/dst are wave-uniform (c spans the lanes): readfirstlane moves them
//    to SGPRs so the EA row loads take the SMEM path (s_load) and the 64 FMAs
//    are v_fmac v,s,v.
// ---------------------------------------------------------------------------
__global__ __launch_bounds__(256, 3) void edge_kernel(
    const float* __restrict__ P, const float* __restrict__ EA,
    const int* __restrict__ ei,
    const float* __restrict__ Wfe, const float* __restrict__ Wse,  // (32,128) each
    const float* __restrict__ bf, const float* __restrict__ bs,
    float* __restrict__ agg)
{
    __shared__ float WfL[4096];
    __shared__ float WsL[4096];
    __shared__ float occ_pad[5120];   // 20 KB pad -> 52 KB total -> 3 blocks/CU

    // Cooperative stage of weights into LDS (float4, coalesced).
    for (int i = threadIdx.x; i < 1024; i += 256) {
        ((float4*)WfL)[i] = ((const float4*)Wfe)[i];
        ((float4*)WsL)[i] = ((const float4*)Wse)[i];
    }
    // Keep occ_pad alive: condition is never true at runtime but not provable.
    if (ei[0] == -123456789) occ_pad[threadIdx.x] = 0.0f;
    __syncthreads();

    const int c = threadIdx.x & 127;
    const int sub = threadIdx.x >> 7;   // wave-uniform (waves 0,1 -> 0; 2,3 -> 1)

    // LDS -> registers, once. Non-rematerializable.
    float wf[32], ws[32];
    #pragma unroll
    for (int k = 0; k < 32; ++k) { wf[k] = WfL[k*128 + c]; ws[k] = WsL[k*128 + c]; }

    const float bfc = bf[c], bsc = bs[c];
    const int stride = gridDim.x * 2;
    const int* srcA = ei;
    const int* dstA = ei + N_EDGES;

    for (int e0 = blockIdx.x * 2 + sub; e0 < N_EDGES; e0 += stride) {
        int e = __builtin_amdgcn_readfirstlane(e0);
        int s = __builtin_amdgcn_readfirstlane(srcA[e]);
        int d = __builtin_amdgcn_readfirstlane(dstA[e]);

        // EA row: wave-uniform address -> scalar loads feeding v_fmac v,s,v.
        const float* ea = EA + (size_t)e * EDGE_DIM;
        float fd = 0.0f, gd = 0.0f;
        #pragma unroll
        for (int k = 0; k < 32; ++k) {
            float evk = ea[k];
            fd += evk * wf[k];
            gd += evk * ws[k];
        }

        float2 vd = *(const float2*)(P + (size_t)d * 512 + 2*c);
        float2 vs = *(const float2*)(P + (size_t)s * 512 + 256 + 2*c);
        float f = bfc + vd.x + vs.x + fd;
        float g = bsc + vd.y + vs.y + gd;
        float sig = __builtin_amdgcn_rcpf(1.0f + __expf(-f));
        float sp  = fmaxf(g, 0.0f) + __logf(1.0f + __expf(-fabsf(g)));
        atomicAdd(agg + (size_t)d * HIDDEN + c, sig * sp);
    }
}

// ---------------------------------------------------------------------------
// H = relu(H + agg)
// ---------------------------------------------------------------------------
__global__ __launch_bounds__(256) void update_kernel(
    float* __restrict__ H, const float* __restrict__ agg)
{
    int idx = blockIdx.x * 256 + threadIdx.x;
    if (idx >= N_NODES * HIDDEN) return;
    H[idx] = fmaxf(H[idx] + agg[idx], 0.0f);
}

// ---------------------------------------------------------------------------
// Pool: per-graph sums + counts (batch sorted; run-length then atomic).
// ---------------------------------------------------------------------------
__global__ __launch_bounds__(128) void pool_kernel(
    const float* __restrict__ H, const int* __restrict__ batch,
    float* __restrict__ gsum, float* __restrict__ gcnt)
{
    const int c = threadIdx.x;
    const int n0 = blockIdx.x * 128;
    float acc = 0.0f;
    int cur = -1;
    for (int i = 0; i < 128; ++i) {
        int n = n0 + i;
        if (n >= N_NODES) break;
        int g = batch[n];
        if (g != cur) {
            if (cur >= 0) atomicAdd(gsum + (size_t)cur * HIDDEN + c, acc);
            cur = g; acc = 0.0f;
        }
        acc += H[(size_t)n * HIDDEN + c];
    }
    if (cur >= 0) atomicAdd(gsum + (size_t)cur * HIDDEN + c, acc);

    if (c == 0) {
        int curg = -1; float run = 0.0f;
        for (int i = 0; i < 128; ++i) {
            int n = n0 + i;
            if (n >= N_NODES) break;
            int g = batch[n];
            if (g != curg) {
                if (curg >= 0) atomicAdd(gcnt + curg, run);
                curg = g; run = 0.0f;
            }
            run += 1.0f;
        }
        if (curg >= 0) atomicAdd(gcnt + curg, run);
    }
}

// ---------------------------------------------------------------------------
// Final MLP: g = relu((gsum/cnt) @ W1 + b1); out = g @ Wh^T + bh
// ---------------------------------------------------------------------------
__global__ __launch_bounds__(128) void head_kernel(
    const float* __restrict__ gsum, const float* __restrict__ gcnt,
    const float* __restrict__ W1, const float* __restrict__ b1,
    const float* __restrict__ Wh, const float* __restrict__ bh,
    float* __restrict__ out)
{
    __shared__ float gavg[128];
    __shared__ float g1[128];
    const int g = blockIdx.x, c = threadIdx.x;
    float cnt = fmaxf(gcnt[g], 1.0f);
    gavg[c] = gsum[(size_t)g * HIDDEN + c] / cnt;
    __syncthreads();
    float acc = b1[c];
    for (int k = 0; k < 128; ++k) acc += gavg[k] * W1[k*128 + c];
    g1[c] = fmaxf(acc, 0.0f);
    __syncthreads();
    if (c < 5) {
        float o = bh[c];
        for (int k = 0; k < 128; ++k) o += g1[k] * Wh[c*128 + k];
        out[(size_t)g * 5 + c] = o;
    }
}

// ---------------------------------------------------------------------------
// Launch
// ---------------------------------------------------------------------------
extern "C" void kernel_launch(void* const* d_in, const int* in_sizes, int n_in,
                              void* d_out, int out_size, void* d_ws, size_t ws_size,
                              hipStream_t stream) {
    const float* x        = (const float*)d_in[0];
    const int*   ei       = (const int*)  d_in[1];
    const float* EA       = (const float*)d_in[2];
    const int*   batch    = (const int*)  d_in[3];
    const float* Wf1      = (const float*)d_in[4];
    const float* bf1      = (const float*)d_in[5];
    const float* Ws1      = (const float*)d_in[6];
    const float* bs1      = (const float*)d_in[7];
    const float* Wp       = (const float*)d_in[8];
    const float* bp       = (const float*)d_in[9];
    const float* Wf_convs = (const float*)d_in[10];
    const float* bf_convs = (const float*)d_in[11];
    const float* Ws_convs = (const float*)d_in[12];
    const float* bs_convs = (const float*)d_in[13];
    const float* W1       = (const float*)d_in[14];
    const float* b1       = (const float*)d_in[15];
    const float* W_heads  = (const float*)d_in[16];
    const float* b_heads  = (const float*)d_in[17];
    float* out = (float*)d_out;

    float* ws = (float*)d_ws;
    // workspace layout (floats), offsets 64-aligned
    float* agg0 = ws + 0;                       // 150000
    float* H    = ws + 150016;                  // 6,400,000
    float* P    = ws + 6550016;                 // 25,600,000
    float* agg  = ws + 32150016;                // 6,400,000
    float* Wcat = ws + 38550016;                // 131072 (2 layers x 128 x 512)
    float* gsum = ws + 38681088;                // 32768
    float* gcnt = ws + 38713856;                // 256

    // conv1
    hipMemsetAsync(agg0, 0, (size_t)N_NODES * 3 * sizeof(float), stream);
    conv1_kernel<<<(N_EDGES + 255)/256, 256, 0, stream>>>(x, ei, EA, Wf1, bf1, Ws1, bs1, agg0);
    // proj
    proj_kernel<<<(N_NODES*HIDDEN + 255)/256, 256, 0, stream>>>(x, agg0, Wp, bp, H);
    // repack weights for both layers
    repack_kernel<<<(2*128*512 + 255)/256, 256, 0, stream>>>(Wf_convs, Ws_convs, Wcat);

    for (int l = 0; l < 2; ++l) {
        const float* Wcat_l = Wcat + (size_t)l * 128 * 512;
        const float* Wfe = Wf_convs + (size_t)l * ZIN * HIDDEN + 256*128;
        const float* Wse = Ws_convs + (size_t)l * ZIN * HIDDEN + 256*128;
        const float* bfl = bf_convs + (size_t)l * HIDDEN;
        const float* bsl = bs_convs + (size_t)l * HIDDEN;
        // P = H @ Wcat_l  (50000 x 128 x 512)
        dim3 ggrid(512/64, (N_NODES + 63)/64);
        gemm64<<<ggrid, 256, 0, stream>>>(H, Wcat_l, P, N_NODES, 512, 128);
        // agg = 0; edge messages
        hipMemsetAsync(agg, 0, (size_t)N_NODES * HIDDEN * sizeof(float), stream);
        edge_kernel<<<2048, 256, 0, stream>>>(P, EA, ei, Wfe, Wse, bfl, bsl, agg);
        // H = relu(H + agg)
        update_kernel<<<(N_NODES*HIDDEN + 255)/256, 256, 0, stream>>>(H, agg);
    }

    // pool + heads
    hipMemsetAsync(gsum, 0, (size_t)(NUM_GRAPHS * HIDDEN + NUM_GRAPHS) * sizeof(float), stream);
    pool_kernel<<<(N_NODES + 127)/128, 128, 0, stream>>>(H, batch, gsum, gcnt);
    head_kernel<<<NUM_GRAPHS, 128, 0, stream>>>(gsum, gcnt, W1, b1, W_heads, b_heads, out);
}

// Round 5
// 1398.547 us; speedup vs baseline: 1.6597x; 1.0664x over previous
//
#include <hip/hip_runtime.h>
#include <hip/hip_bf16.h>
#include <math.h>

// Problem constants (fixed by the reference)
#define N_NODES 50000
#define N_EDGES 800000
#define NODE_DIM 3
#define EDGE_DIM 32
#define HIDDEN 128
#define NUM_GRAPHS 256
#define ZIN (2*HIDDEN + EDGE_DIM)   // 288

// ---------------------------------------------------------------------------
// conv1: CGConv on 3-dim features. One thread per edge.
// ---------------------------------------------------------------------------
__global__ __launch_bounds__(256) void conv1_kernel(
    const float* __restrict__ x, const int* __restrict__ ei,
    const float* __restrict__ EA,
    const float* __restrict__ Wf1, const float* __restrict__ bf1,
    const float* __restrict__ Ws1, const float* __restrict__ bs1,
    float* __restrict__ agg0)
{
    __shared__ float WfL[38*3], WsL[38*3], bfL[3], bsL[3];
    if (threadIdx.x < 114) {
        WfL[threadIdx.x] = Wf1[threadIdx.x];
        WsL[threadIdx.x] = Ws1[threadIdx.x];
    }
    if (threadIdx.x < 3) { bfL[threadIdx.x] = bf1[threadIdx.x]; bsL[threadIdx.x] = bs1[threadIdx.x]; }
    __syncthreads();

    int e = blockIdx.x * 256 + threadIdx.x;
    if (e >= N_EDGES) return;
    int s = ei[e];
    int d = ei[N_EDGES + e];

    float z[38];
    z[0] = x[d*3+0]; z[1] = x[d*3+1]; z[2] = x[d*3+2];
    z[3] = x[s*3+0]; z[4] = x[s*3+1]; z[5] = x[s*3+2];
    const float4* ep = (const float4*)(EA + (size_t)e * EDGE_DIM);
    #pragma unroll
    for (int q = 0; q < 8; ++q) {
        float4 v = ep[q];
        z[6+4*q+0] = v.x; z[6+4*q+1] = v.y; z[6+4*q+2] = v.z; z[6+4*q+3] = v.w;
    }
    float f[3], g[3];
    #pragma unroll
    for (int c = 0; c < 3; ++c) { f[c] = bfL[c]; g[c] = bsL[c]; }
    #pragma unroll
    for (int j = 0; j < 38; ++j) {
        #pragma unroll
        for (int c = 0; c < 3; ++c) {
            f[c] += z[j] * WfL[j*3+c];
            g[c] += z[j] * WsL[j*3+c];
        }
    }
    #pragma unroll
    for (int c = 0; c < 3; ++c) {
        float sig = __builtin_amdgcn_rcpf(1.0f + __expf(-f[c]));
        float sp  = fmaxf(g[c], 0.0f) + __logf(1.0f + __expf(-fabsf(g[c])));
        atomicAdd(agg0 + (size_t)d*3 + c, sig * sp);
    }
}

// ---------------------------------------------------------------------------
// proj: H[n][c] = relu(bp[c] + sum_j (x[n][j]+agg0[n][j]) * Wp[j][c])
// ---------------------------------------------------------------------------
__global__ __launch_bounds__(256) void proj_kernel(
    const float* __restrict__ x, const float* __restrict__ agg0,
    const float* __restrict__ Wp, const float* __restrict__ bp,
    float* __restrict__ H)
{
    int idx = blockIdx.x * 256 + threadIdx.x;
    if (idx >= N_NODES * HIDDEN) return;
    int n = idx >> 7, c = idx & 127;
    float h0 = x[n*3+0] + agg0[n*3+0];
    float h1 = x[n*3+1] + agg0[n*3+1];
    float h2 = x[n*3+2] + agg0[n*3+2];
    float v = bp[c] + h0*Wp[0*128+c] + h1*Wp[1*128+c] + h2*Wp[2*128+c];
    H[idx] = fmaxf(v, 0.0f);
}

// ---------------------------------------------------------------------------
// Repack node-path weights into Wcat (128 x 512), INTERLEAVED column layout:
//   n in [0,256):   n = 2c+t  -> t=0: Wf[k][c] (dst rows), t=1: Ws[k][c]
//   n in [256,512): n-256=2c+t-> t=0: Wf[128+k][c] (src),  t=1: Ws[128+k][c]
// So P[n][2c],P[n][2c+1] = (f_dst,s_dst) and P[n][256+2c..] = (f_src,s_src).
// ---------------------------------------------------------------------------
__global__ __launch_bounds__(256) void repack_kernel(
    const float* __restrict__ Wf, const float* __restrict__ Ws,
    float* __restrict__ Wcat)
{
    int idx = blockIdx.x * 256 + threadIdx.x;   // 2 * 128 * 512 total
    if (idx >= 2*128*512) return;
    int l = idx >> 16;
    int rem = idx & 65535;
    int k = rem >> 9, n = rem & 511;
    const float* wf = Wf + (size_t)l * ZIN * HIDDEN;
    const float* wsp = Ws + (size_t)l * ZIN * HIDDEN;
    int half = n >> 8;          // 0 = dst rows, 1 = src rows
    int within = n & 255;
    int cc = within >> 1;
    int t = within & 1;         // 0 = Wf, 1 = Ws
    const float* W = t ? wsp : wf;
    Wcat[idx] = W[(size_t)(half*128 + k)*128 + cc];
}

// ---------------------------------------------------------------------------
// Repack EDGE-path weights into WL2: (2 layers, 32 k, 128 c) of float2(wf,ws).
// One ds_read_b64 in the edge kernel then fetches both weights for (k,c).
// ---------------------------------------------------------------------------
__global__ __launch_bounds__(256) void repack_edge_kernel(
    const float* __restrict__ Wf, const float* __restrict__ Ws,
    float2* __restrict__ WL2)
{
    int idx = blockIdx.x * 256 + threadIdx.x;   // 2 * 32 * 128
    if (idx >= 2*32*128) return;
    int l = idx >> 12;
    int rem = idx & 4095;       // k*128 + c
    const float* wfe = Wf + (size_t)l * ZIN * HIDDEN + 256*128;
    const float* wse = Ws + (size_t)l * ZIN * HIDDEN + 256*128;
    WL2[idx] = make_float2(wfe[rem], wse[rem]);
}

// ---------------------------------------------------------------------------
// GEMM: C(MxN) = A(MxK) @ B(KxN), fp32, 64x64 tile, 4x4 per thread, k-step 16
// ---------------------------------------------------------------------------
__global__ __launch_bounds__(256) void gemm64(
    const float* __restrict__ A, const float* __restrict__ B,
    float* __restrict__ C, int M, int N, int K)
{
    __shared__ float As[16][65];
    __shared__ float Bs[16][65];
    const int tid = threadIdx.x;
    const int tx = tid & 15;
    const int ty = tid >> 4;
    const int colBase = blockIdx.x * 64;
    const int rowBase = blockIdx.y * 64;
    const int am = tid >> 2;          // 0..63
    const int ak = (tid & 3) * 4;     // 0,4,8,12
    const int bk = tid >> 4;          // 0..15
    const int bn = (tid & 15) * 4;

    float acc[4][4];
    #pragma unroll
    for (int i = 0; i < 4; ++i)
        #pragma unroll
        for (int j = 0; j < 4; ++j) acc[i][j] = 0.0f;

    for (int k0 = 0; k0 < K; k0 += 16) {
        int arow = rowBase + am;
        float4 a4 = make_float4(0.f, 0.f, 0.f, 0.f);
        if (arow < M) a4 = *(const float4*)(A + (size_t)arow * K + k0 + ak);
        float4 b4 = *(const float4*)(B + (size_t)(k0 + bk) * N + colBase + bn);
        __syncthreads();
        As[ak+0][am] = a4.x; As[ak+1][am] = a4.y; As[ak+2][am] = a4.z; As[ak+3][am] = a4.w;
        Bs[bk][bn+0] = b4.x; Bs[bk][bn+1] = b4.y; Bs[bk][bn+2] = b4.z; Bs[bk][bn+3] = b4.w;
        __syncthreads();
        #pragma unroll
        for (int k = 0; k < 16; ++k) {
            float a0 = As[k][ty*4+0], a1 = As[k][ty*4+1], a2 = As[k][ty*4+2], a3 = As[k][ty*4+3];
            float b0 = Bs[k][tx*4+0], b1 = Bs[k][tx*4+1], b2 = Bs[k][tx*4+2], b3 = Bs[k][tx*4+3];
            acc[0][0] += a0*b0; acc[0][1] += a0*b1; acc[0][2] += a0*b2; acc[0][3] += a0*b3;
            acc[1][0] += a1*b0; acc[1][1] += a1*b1; acc[1][2] += a1*b2; acc[1][3] += a1*b3;
            acc[2][0] += a2*b0; acc[2][1] += a2*b1; acc[2][2] += a2*b2; acc[2][3] += a2*b3;
            acc[3][0] += a3*b0; acc[3][1] += a3*b1; acc[3][2] += a3*b2; acc[3][3] += a3*b3;
        }
    }
    #pragma unroll
    for (int i = 0; i < 4; ++i) {
        int r = rowBase + ty*4 + i;
        if (r >= M) continue;
        #pragma unroll
        for (int j = 0; j < 4; ++j) {
            C[(size_t)r * N + colBase + tx*4 + j] = acc[i][j];
        }
    }
}

// ---------------------------------------------------------------------------
// Fused edge kernel, v5.
// R4 diagnosis: LDS-instruction-bound (64 ds_read_b32/thread/edge = 25.6 GB
// LDS traffic/layer ~= 371 us floor; measured 438). Weight-read volume per
// edge is invariant under thread layout -- only cross-edge reuse cuts it:
//  - (wf,ws) packed as float2 -> ONE ds_read_b64 per (k) instead of two b32.
//  - U=2 edge unroll: each weight read feeds 4 FMAs (2 edges x f,s)
//    -> 16 LDS instrs/thread/edge (4x fewer than R4).
//  - EA rows of both edges are consecutive (e1=e0+1) -> one scalar
//    s_load_dwordx16 batch (64 floats in SGPRs), FMAs are v_fmac v,s,v.
// ---------------------------------------------------------------------------
__global__ __launch_bounds__(256) void edge_kernel(
    const float* __restrict__ P, const float* __restrict__ EA,
    const int* __restrict__ ei,
    const float2* __restrict__ WL2,   // (32,128) float2 (wf,ws), this layer
    const float* __restrict__ bf, const float* __restrict__ bs,
    float* __restrict__ agg)
{
    __shared__ float2 WL[32*128];     // 32 KB

    // Cooperative stage (float4 = one float2 pair per thread-iter, coalesced).
    for (int i = threadIdx.x; i < 2048; i += 256) {
        ((float4*)WL)[i] = ((const float4*)WL2)[i];
    }
    __syncthreads();

    const int c = threadIdx.x & 127;
    const int sub = threadIdx.x >> 7;   // wave-uniform
    const float bfc = bf[c], bsc = bs[c];
    const int stride = gridDim.x * 4;
    const int* srcA = ei;
    const int* dstA = ei + N_EDGES;

    for (int eb = blockIdx.x * 4 + sub * 2; eb < N_EDGES; eb += stride) {
        int e0 = __builtin_amdgcn_readfirstlane(eb);
        int e1 = e0 + 1;
        int s0 = __builtin_amdgcn_readfirstlane(srcA[e0]);
        int d0 = __builtin_amdgcn_readfirstlane(dstA[e0]);
        int s1 = __builtin_amdgcn_readfirstlane(srcA[e1]);
        int d1 = __builtin_amdgcn_readfirstlane(dstA[e1]);

        // 64 consecutive floats, wave-uniform address -> SMEM path.
        const float* ea0 = EA + (size_t)e0 * EDGE_DIM;
        const float* ea1 = ea0 + EDGE_DIM;

        float fd0 = 0.0f, gd0 = 0.0f, fd1 = 0.0f, gd1 = 0.0f;
        #pragma unroll
        for (int k = 0; k < 32; ++k) {
            float2 w = WL[k*128 + c];     // ds_read_b64, shared by both edges
            float a0 = ea0[k];            // SGPR
            float a1 = ea1[k];            // SGPR
            fd0 += a0 * w.x; gd0 += a0 * w.y;
            fd1 += a1 * w.x; gd1 += a1 * w.y;
        }

        float2 vd0 = *(const float2*)(P + (size_t)d0 * 512 + 2*c);
        float2 vs0 = *(const float2*)(P + (size_t)s0 * 512 + 256 + 2*c);
        float2 vd1 = *(const float2*)(P + (size_t)d1 * 512 + 2*c);
        float2 vs1 = *(const float2*)(P + (size_t)s1 * 512 + 256 + 2*c);

        float f0 = bfc + vd0.x + vs0.x + fd0;
        float g0 = bsc + vd0.y + vs0.y + gd0;
        float f1 = bfc + vd1.x + vs1.x + fd1;
        float g1 = bsc + vd1.y + vs1.y + gd1;

        float sig0 = __builtin_amdgcn_rcpf(1.0f + __expf(-f0));
        float sp0  = fmaxf(g0, 0.0f) + __logf(1.0f + __expf(-fabsf(g0)));
        float sig1 = __builtin_amdgcn_rcpf(1.0f + __expf(-f1));
        float sp1  = fmaxf(g1, 0.0f) + __logf(1.0f + __expf(-fabsf(g1)));

        atomicAdd(agg + (size_t)d0 * HIDDEN + c, sig0 * sp0);
        atomicAdd(agg + (size_t)d1 * HIDDEN + c, sig1 * sp1);
    }
}

// ---------------------------------------------------------------------------
// H = relu(H + agg)
// ---------------------------------------------------------------------------
__global__ __launch_bounds__(256) void update_kernel(
    float* __restrict__ H, const float* __restrict__ agg)
{
    int idx = blockIdx.x * 256 + threadIdx.x;
    if (idx >= N_NODES * HIDDEN) return;
    H[idx] = fmaxf(H[idx] + agg[idx], 0.0f);
}

// ---------------------------------------------------------------------------
// Pool: per-graph sums + counts (batch sorted; run-length then atomic).
// ---------------------------------------------------------------------------
__global__ __launch_bounds__(128) void pool_kernel(
    const float* __restrict__ H, const int* __restrict__ batch,
    float* __restrict__ gsum, float* __restrict__ gcnt)
{
    const int c = threadIdx.x;
    const int n0 = blockIdx.x * 128;
    float acc = 0.0f;
    int cur = -1;
    for (int i = 0; i < 128; ++i) {
        int n = n0 + i;
        if (n >= N_NODES) break;
        int g = batch[n];
        if (g != cur) {
            if (cur >= 0) atomicAdd(gsum + (size_t)cur * HIDDEN + c, acc);
            cur = g; acc = 0.0f;
        }
        acc += H[(size_t)n * HIDDEN + c];
    }
    if (cur >= 0) atomicAdd(gsum + (size_t)cur * HIDDEN + c, acc);

    if (c == 0) {
        int curg = -1; float run = 0.0f;
        for (int i = 0; i < 128; ++i) {
            int n = n0 + i;
            if (n >= N_NODES) break;
            int g = batch[n];
            if (g != curg) {
                if (curg >= 0) atomicAdd(gcnt + curg, run);
                curg = g; run = 0.0f;
            }
            run += 1.0f;
        }
        if (curg >= 0) atomicAdd(gcnt + curg, run);
    }
}

// ---------------------------------------------------------------------------
// Final MLP: g = relu((gsum/cnt) @ W1 + b1); out = g @ Wh^T + bh
// ---------------------------------------------------------------------------
__global__ __launch_bounds__(128) void head_kernel(
    const float* __restrict__ gsum, const float* __restrict__ gcnt,
    const float* __restrict__ W1, const float* __restrict__ b1,
    const float* __restrict__ Wh, const float* __restrict__ bh,
    float* __restrict__ out)
{
    __shared__ float gavg[128];
    __shared__ float g1[128];
    const int g = blockIdx.x, c = threadIdx.x;
    float cnt = fmaxf(gcnt[g], 1.0f);
    gavg[c] = gsum[(size_t)g * HIDDEN + c] / cnt;
    __syncthreads();
    float acc = b1[c];
    for (int k = 0; k < 128; ++k) acc += gavg[k] * W1[k*128 + c];
    g1[c] = fmaxf(acc, 0.0f);
    __syncthreads();
    if (c < 5) {
        float o = bh[c];
        for (int k = 0; k < 128; ++k) o += g1[k] * Wh[c*128 + k];
        out[(size_t)g * 5 + c] = o;
    }
}

// ---------------------------------------------------------------------------
// Launch
// ---------------------------------------------------------------------------
extern "C" void kernel_launch(void* const* d_in, const int* in_sizes, int n_in,
                              void* d_out, int out_size, void* d_ws, size_t ws_size,
                              hipStream_t stream) {
    const float* x        = (const float*)d_in[0];
    const int*   ei       = (const int*)  d_in[1];
    const float* EA       = (const float*)d_in[2];
    const int*   batch    = (const int*)  d_in[3];
    const float* Wf1      = (const float*)d_in[4];
    const float* bf1      = (const float*)d_in[5];
    const float* Ws1      = (const float*)d_in[6];
    const float* bs1      = (const float*)d_in[7];
    const float* Wp       = (const float*)d_in[8];
    const float* bp       = (const float*)d_in[9];
    const float* Wf_convs = (const float*)d_in[10];
    const float* bf_convs = (const float*)d_in[11];
    const float* Ws_convs = (const float*)d_in[12];
    const float* bs_convs = (const float*)d_in[13];
    const float* W1       = (const float*)d_in[14];
    const float* b1       = (const float*)d_in[15];
    const float* W_heads  = (const float*)d_in[16];
    const float* b_heads  = (const float*)d_in[17];
    float* out = (float*)d_out;

    float* ws = (float*)d_ws;
    // workspace layout (floats), offsets 64-aligned
    float* agg0 = ws + 0;                       // 150000
    float* H    = ws + 150016;                  // 6,400,000
    float* P    = ws + 6550016;                 // 25,600,000
    float* agg  = ws + 32150016;                // 6,400,000
    float* Wcat = ws + 38550016;                // 131072 (2 layers x 128 x 512)
    float* gsum = ws + 38681088;                // 32768
    float* gcnt = ws + 38713856;                // 256
    float2* WL2 = (float2*)(ws + 38714112);     // 2 layers x 32 x 128 float2 (64 KB)

    // conv1
    hipMemsetAsync(agg0, 0, (size_t)N_NODES * 3 * sizeof(float), stream);
    conv1_kernel<<<(N_EDGES + 255)/256, 256, 0, stream>>>(x, ei, EA, Wf1, bf1, Ws1, bs1, agg0);
    // proj
    proj_kernel<<<(N_NODES*HIDDEN + 255)/256, 256, 0, stream>>>(x, agg0, Wp, bp, H);
    // repack weights for both layers
    repack_kernel<<<(2*128*512 + 255)/256, 256, 0, stream>>>(Wf_convs, Ws_convs, Wcat);
    repack_edge_kernel<<<(2*32*128 + 255)/256, 256, 0, stream>>>(Wf_convs, Ws_convs, WL2);

    for (int l = 0; l < 2; ++l) {
        const float* Wcat_l = Wcat + (size_t)l * 128 * 512;
        const float2* WL2_l = WL2 + (size_t)l * 32 * 128;
        const float* bfl = bf_convs + (size_t)l * HIDDEN;
        const float* bsl = bs_convs + (size_t)l * HIDDEN;
        // P = H @ Wcat_l  (50000 x 128 x 512)
        dim3 ggrid(512/64, (N_NODES + 63)/64);
        gemm64<<<ggrid, 256, 0, stream>>>(H, Wcat_l, P, N_NODES, 512, 128);
        // agg = 0; edge messages
        hipMemsetAsync(agg, 0, (size_t)N_NODES * HIDDEN * sizeof(float), stream);
        edge_kernel<<<2048, 256, 0, stream>>>(P, EA, ei, WL2_l, bfl, bsl, agg);
        // H = relu(H + agg)
        update_kernel<<<(N_NODES*HIDDEN + 255)/256, 256, 0, stream>>>(H, agg);
    }

    // pool + heads
    hipMemsetAsync(gsum, 0, (size_t)(NUM_GRAPHS * HIDDEN + NUM_GRAPHS) * sizeof(float), stream);
    pool_kernel<<<(N_NODES + 127)/128, 128, 0, stream>>>(H, batch, gsum, gcnt);
    head_kernel<<<NUM_GRAPHS, 128, 0, stream>>>(gsum, gcnt, W1, b1, W_heads, b_heads, out);
}

// Round 6
// 1241.786 us; speedup vs baseline: 1.8692x; 1.1262x over previous
//
#include <hip/hip_runtime.h>
#include <hip/hip_bf16.h>
#include <math.h>

// Problem constants (fixed by the reference)
#define N_NODES 50000
#define N_EDGES 800000
#define NODE_DIM 3
#define EDGE_DIM 32
#define HIDDEN 128
#define NUM_GRAPHS 256
#define ZIN (2*HIDDEN + EDGE_DIM)   // 288

typedef __attribute__((ext_vector_type(8))) short short8;
typedef __attribute__((ext_vector_type(4))) float f32x4;

// fp32 -> bf16 (RNE), finite inputs
__device__ __forceinline__ unsigned short f2bf(float x) {
    unsigned u = __float_as_uint(x);
    u += 0x7FFFu + ((u >> 16) & 1u);
    return (unsigned short)(u >> 16);
}

// ---------------------------------------------------------------------------
// conv1: CGConv on 3-dim features. One thread per edge.
// ---------------------------------------------------------------------------
__global__ __launch_bounds__(256) void conv1_kernel(
    const float* __restrict__ x, const int* __restrict__ ei,
    const float* __restrict__ EA,
    const float* __restrict__ Wf1, const float* __restrict__ bf1,
    const float* __restrict__ Ws1, const float* __restrict__ bs1,
    float* __restrict__ agg0)
{
    __shared__ float WfL[38*3], WsL[38*3], bfL[3], bsL[3];
    if (threadIdx.x < 114) {
        WfL[threadIdx.x] = Wf1[threadIdx.x];
        WsL[threadIdx.x] = Ws1[threadIdx.x];
    }
    if (threadIdx.x < 3) { bfL[threadIdx.x] = bf1[threadIdx.x]; bsL[threadIdx.x] = bs1[threadIdx.x]; }
    __syncthreads();

    int e = blockIdx.x * 256 + threadIdx.x;
    if (e >= N_EDGES) return;
    int s = ei[e];
    int d = ei[N_EDGES + e];

    float z[38];
    z[0] = x[d*3+0]; z[1] = x[d*3+1]; z[2] = x[d*3+2];
    z[3] = x[s*3+0]; z[4] = x[s*3+1]; z[5] = x[s*3+2];
    const float4* ep = (const float4*)(EA + (size_t)e * EDGE_DIM);
    #pragma unroll
    for (int q = 0; q < 8; ++q) {
        float4 v = ep[q];
        z[6+4*q+0] = v.x; z[6+4*q+1] = v.y; z[6+4*q+2] = v.z; z[6+4*q+3] = v.w;
    }
    float f[3], g[3];
    #pragma unroll
    for (int c = 0; c < 3; ++c) { f[c] = bfL[c]; g[c] = bsL[c]; }
    #pragma unroll
    for (int j = 0; j < 38; ++j) {
        #pragma unroll
        for (int c = 0; c < 3; ++c) {
            f[c] += z[j] * WfL[j*3+c];
            g[c] += z[j] * WsL[j*3+c];
        }
    }
    #pragma unroll
    for (int c = 0; c < 3; ++c) {
        float sig = __builtin_amdgcn_rcpf(1.0f + __expf(-f[c]));
        float sp  = fmaxf(g[c], 0.0f) + __logf(1.0f + __expf(-fabsf(g[c])));
        atomicAdd(agg0 + (size_t)d*3 + c, sig * sp);
    }
}

// ---------------------------------------------------------------------------
// proj: H[n][c] = relu(bp[c] + sum_j (x[n][j]+agg0[n][j]) * Wp[j][c])
// ---------------------------------------------------------------------------
__global__ __launch_bounds__(256) void proj_kernel(
    const float* __restrict__ x, const float* __restrict__ agg0,
    const float* __restrict__ Wp, const float* __restrict__ bp,
    float* __restrict__ H)
{
    int idx = blockIdx.x * 256 + threadIdx.x;
    if (idx >= N_NODES * HIDDEN) return;
    int n = idx >> 7, c = idx & 127;
    float h0 = x[n*3+0] + agg0[n*3+0];
    float h1 = x[n*3+1] + agg0[n*3+1];
    float h2 = x[n*3+2] + agg0[n*3+2];
    float v = bp[c] + h0*Wp[0*128+c] + h1*Wp[1*128+c] + h2*Wp[2*128+c];
    H[idx] = fmaxf(v, 0.0f);
}

// ---------------------------------------------------------------------------
// Repack node-path weights DIRECTLY into MFMA B-fragment layout (bf16).
// Logical Wcat (128 x 512) columns: n=2c+t in [0,256) -> (dst, t=0:Wf,t=1:Ws);
// n-256=2c+t in [256,512) -> (src).  (Same P column semantics as before.)
// Fragment layout: Bfrag[l][ntile 0..31][kc 0..3][lane 0..63][j 0..7] where
// the value is Wcat[k = kc*32 + (lane>>4)*8 + j][n = ntile*16 + (lane&15)].
// One thread per (l,ntile,kc,lane) -> 8 bf16 = one dwordx4 store.
// ---------------------------------------------------------------------------
__global__ __launch_bounds__(256) void repack_frag_kernel(
    const float* __restrict__ Wf, const float* __restrict__ Ws,
    unsigned short* __restrict__ Bfrag)
{
    int idx = blockIdx.x * 256 + threadIdx.x;   // 2*32*4*64 = 16384
    if (idx >= 2*32*4*64) return;
    int lane = idx & 63;
    int kc   = (idx >> 6) & 3;
    int nt   = (idx >> 8) & 31;
    int l    = idx >> 13;
    const float* wf  = Wf + (size_t)l * ZIN * HIDDEN;
    const float* wsp = Ws + (size_t)l * ZIN * HIDDEN;
    int n = nt*16 + (lane & 15);
    int half = n >> 8;           // 0 = dst rows, 1 = src rows
    int within = n & 255;
    int cc = within >> 1;
    int t = within & 1;
    const float* W = t ? wsp : wf;
    unsigned short vals[8];
    #pragma unroll
    for (int j = 0; j < 8; ++j) {
        int k = kc*32 + (lane >> 4)*8 + j;
        vals[j] = f2bf(W[(size_t)(half*128 + k)*128 + cc]);
    }
    *(short8*)(Bfrag + (size_t)idx * 8) = *(short8*)vals;
}

// ---------------------------------------------------------------------------
// MFMA GEMM: P(50000x512) = H(50000x128, fp32->bf16 in-kernel) @ Wcat(bf16).
// Block = 256 threads = 4 waves. Block tile: 64 rows x 256 cols.
// Wave tile: 16 rows x 256 cols = 16 MFMA tiles (16x16), K=128 in 4 chunks.
// A frag: lane holds H[row = wtile+lane&15][k = kc*32 + quad*8 + j].
// D tile: col = colBase+nt*16+(lane&15), row = wtile + quad*4 + reg.
// Accum fp32; P written fp32 -> edge kernel untouched.
// ---------------------------------------------------------------------------
__global__ __launch_bounds__(256) void gemm_mfma(
    const float* __restrict__ H, const unsigned short* __restrict__ Bfrag,
    float* __restrict__ P)
{
    const int lane = threadIdx.x & 63;
    const int wave = threadIdx.x >> 6;
    const int m    = lane & 15;
    const int quad = lane >> 4;
    const int rowA = blockIdx.y * 64 + wave * 16 + m;      // may reach 50047: reads land in ws (safe), stores masked
    const int colBase = blockIdx.x * 256;

    // A fragments: 4 K-chunks, cvt fp32->bf16 in registers.
    const float* hrow = H + (size_t)rowA * 128;
    short8 a[4];
    #pragma unroll
    for (int kc = 0; kc < 4; ++kc) {
        float4 v0 = *(const float4*)(hrow + kc*32 + quad*8);
        float4 v1 = *(const float4*)(hrow + kc*32 + quad*8 + 4);
        unsigned short t[8];
        t[0]=f2bf(v0.x); t[1]=f2bf(v0.y); t[2]=f2bf(v0.z); t[3]=f2bf(v0.w);
        t[4]=f2bf(v1.x); t[5]=f2bf(v1.y); t[6]=f2bf(v1.z); t[7]=f2bf(v1.w);
        a[kc] = *(short8*)t;
    }

    f32x4 acc[16];
    #pragma unroll
    for (int nt = 0; nt < 16; ++nt) acc[nt] = (f32x4){0.f, 0.f, 0.f, 0.f};

    #pragma unroll
    for (int nt = 0; nt < 16; ++nt) {
        int ntg = (colBase >> 4) + nt;     // global n-tile index
        const unsigned short* bp = Bfrag + ((size_t)(ntg*4) * 64 + lane) * 8;
        #pragma unroll
        for (int kc = 0; kc < 4; ++kc) {
            short8 b = *(const short8*)(bp + (size_t)kc * 64 * 8);
            acc[nt] = __builtin_amdgcn_mfma_f32_16x16x32_bf16(a[kc], b, acc[nt], 0, 0, 0);
        }
    }

    const int rowC = blockIdx.y * 64 + wave * 16 + quad * 4;
    #pragma unroll
    for (int nt = 0; nt < 16; ++nt) {
        int col = colBase + nt*16 + m;
        #pragma unroll
        for (int r = 0; r < 4; ++r) {
            int row = rowC + r;
            if (row < N_NODES) P[(size_t)row * 512 + col] = acc[nt][r];
        }
    }
}

// ---------------------------------------------------------------------------
// Repack EDGE-path weights into WL2: (2 layers, 32 k, 128 c) of float2(wf,ws).
// ---------------------------------------------------------------------------
__global__ __launch_bounds__(256) void repack_edge_kernel(
    const float* __restrict__ Wf, const float* __restrict__ Ws,
    float2* __restrict__ WL2)
{
    int idx = blockIdx.x * 256 + threadIdx.x;   // 2 * 32 * 128
    if (idx >= 2*32*128) return;
    int l = idx >> 12;
    int rem = idx & 4095;       // k*128 + c
    const float* wfe = Wf + (size_t)l * ZIN * HIDDEN + 256*128;
    const float* wse = Ws + (size_t)l * ZIN * HIDDEN + 256*128;
    WL2[idx] = make_float2(wfe[rem], wse[rem]);
}

// ---------------------------------------------------------------------------
// Fused edge kernel (unchanged from R5: LDS float2 weights, U=2 edge unroll,
// scalar EA loads). VALU-issue-bound at ~387 us; MFMA-izing it is future work.
// ---------------------------------------------------------------------------
__global__ __launch_bounds__(256) void edge_kernel(
    const float* __restrict__ P, const float* __restrict__ EA,
    const int* __restrict__ ei,
    const float2* __restrict__ WL2,   // (32,128) float2 (wf,ws), this layer
    const float* __restrict__ bf, const float* __restrict__ bs,
    float* __restrict__ agg)
{
    __shared__ float2 WL[32*128];     // 32 KB

    for (int i = threadIdx.x; i < 2048; i += 256) {
        ((float4*)WL)[i] = ((const float4*)WL2)[i];
    }
    __syncthreads();

    const int c = threadIdx.x & 127;
    const int sub = threadIdx.x >> 7;   // wave-uniform
    const float bfc = bf[c], bsc = bs[c];
    const int stride = gridDim.x * 4;
    const int* srcA = ei;
    const int* dstA = ei + N_EDGES;

    for (int eb = blockIdx.x * 4 + sub * 2; eb < N_EDGES; eb += stride) {
        int e0 = __builtin_amdgcn_readfirstlane(eb);
        int e1 = e0 + 1;
        int s0 = __builtin_amdgcn_readfirstlane(srcA[e0]);
        int d0 = __builtin_amdgcn_readfirstlane(dstA[e0]);
        int s1 = __builtin_amdgcn_readfirstlane(srcA[e1]);
        int d1 = __builtin_amdgcn_readfirstlane(dstA[e1]);

        const float* ea0 = EA + (size_t)e0 * EDGE_DIM;
        const float* ea1 = ea0 + EDGE_DIM;

        float fd0 = 0.0f, gd0 = 0.0f, fd1 = 0.0f, gd1 = 0.0f;
        #pragma unroll
        for (int k = 0; k < 32; ++k) {
            float2 w = WL[k*128 + c];     // ds_read_b64, shared by both edges
            float a0 = ea0[k];            // SGPR
            float a1 = ea1[k];            // SGPR
            fd0 += a0 * w.x; gd0 += a0 * w.y;
            fd1 += a1 * w.x; gd1 += a1 * w.y;
        }

        float2 vd0 = *(const float2*)(P + (size_t)d0 * 512 + 2*c);
        float2 vs0 = *(const float2*)(P + (size_t)s0 * 512 + 256 + 2*c);
        float2 vd1 = *(const float2*)(P + (size_t)d1 * 512 + 2*c);
        float2 vs1 = *(const float2*)(P + (size_t)s1 * 512 + 256 + 2*c);

        float f0 = bfc + vd0.x + vs0.x + fd0;
        float g0 = bsc + vd0.y + vs0.y + gd0;
        float f1 = bfc + vd1.x + vs1.x + fd1;
        float g1 = bsc + vd1.y + vs1.y + gd1;

        float sig0 = __builtin_amdgcn_rcpf(1.0f + __expf(-f0));
        float sp0  = fmaxf(g0, 0.0f) + __logf(1.0f + __expf(-fabsf(g0)));
        float sig1 = __builtin_amdgcn_rcpf(1.0f + __expf(-f1));
        float sp1  = fmaxf(g1, 0.0f) + __logf(1.0f + __expf(-fabsf(g1)));

        atomicAdd(agg + (size_t)d0 * HIDDEN + c, sig0 * sp0);
        atomicAdd(agg + (size_t)d1 * HIDDEN + c, sig1 * sp1);
    }
}

// ---------------------------------------------------------------------------
// H = relu(H + agg)
// ---------------------------------------------------------------------------
__global__ __launch_bounds__(256) void update_kernel(
    float* __restrict__ H, const float* __restrict__ agg)
{
    int idx = blockIdx.x * 256 + threadIdx.x;
    if (idx >= N_NODES * HIDDEN) return;
    H[idx] = fmaxf(H[idx] + agg[idx], 0.0f);
}

// ---------------------------------------------------------------------------
// Pool: per-graph sums + counts (batch sorted; run-length then atomic).
// ---------------------------------------------------------------------------
__global__ __launch_bounds__(128) void pool_kernel(
    const float* __restrict__ H, const int* __restrict__ batch,
    float* __restrict__ gsum, float* __restrict__ gcnt)
{
    const int c = threadIdx.x;
    const int n0 = blockIdx.x * 128;
    float acc = 0.0f;
    int cur = -1;
    for (int i = 0; i < 128; ++i) {
        int n = n0 + i;
        if (n >= N_NODES) break;
        int g = batch[n];
        if (g != cur) {
            if (cur >= 0) atomicAdd(gsum + (size_t)cur * HIDDEN + c, acc);
            cur = g; acc = 0.0f;
        }
        acc += H[(size_t)n * HIDDEN + c];
    }
    if (cur >= 0) atomicAdd(gsum + (size_t)cur * HIDDEN + c, acc);

    if (c == 0) {
        int curg = -1; float run = 0.0f;
        for (int i = 0; i < 128; ++i) {
            int n = n0 + i;
            if (n >= N_NODES) break;
            int g = batch[n];
            if (g != curg) {
                if (curg >= 0) atomicAdd(gcnt + curg, run);
                curg = g; run = 0.0f;
            }
            run += 1.0f;
        }
        if (curg >= 0) atomicAdd(gcnt + curg, run);
    }
}

// ---------------------------------------------------------------------------
// Final MLP: g = relu((gsum/cnt) @ W1 + b1); out = g @ Wh^T + bh
// ---------------------------------------------------------------------------
__global__ __launch_bounds__(128) void head_kernel(
    const float* __restrict__ gsum, const float* __restrict__ gcnt,
    const float* __restrict__ W1, const float* __restrict__ b1,
    const float* __restrict__ Wh, const float* __restrict__ bh,
    float* __restrict__ out)
{
    __shared__ float gavg[128];
    __shared__ float g1[128];
    const int g = blockIdx.x, c = threadIdx.x;
    float cnt = fmaxf(gcnt[g], 1.0f);
    gavg[c] = gsum[(size_t)g * HIDDEN + c] / cnt;
    __syncthreads();
    float acc = b1[c];
    for (int k = 0; k < 128; ++k) acc += gavg[k] * W1[k*128 + c];
    g1[c] = fmaxf(acc, 0.0f);
    __syncthreads();
    if (c < 5) {
        float o = bh[c];
        for (int k = 0; k < 128; ++k) o += g1[k] * Wh[c*128 + k];
        out[(size_t)g * 5 + c] = o;
    }
}

// ---------------------------------------------------------------------------
// Launch
// ---------------------------------------------------------------------------
extern "C" void kernel_launch(void* const* d_in, const int* in_sizes, int n_in,
                              void* d_out, int out_size, void* d_ws, size_t ws_size,
                              hipStream_t stream) {
    const float* x        = (const float*)d_in[0];
    const int*   ei       = (const int*)  d_in[1];
    const float* EA       = (const float*)d_in[2];
    const int*   batch    = (const int*)  d_in[3];
    const float* Wf1      = (const float*)d_in[4];
    const float* bf1      = (const float*)d_in[5];
    const float* Ws1      = (const float*)d_in[6];
    const float* bs1      = (const float*)d_in[7];
    const float* Wp       = (const float*)d_in[8];
    const float* bp       = (const float*)d_in[9];
    const float* Wf_convs = (const float*)d_in[10];
    const float* bf_convs = (const float*)d_in[11];
    const float* Ws_convs = (const float*)d_in[12];
    const float* bs_convs = (const float*)d_in[13];
    const float* W1       = (const float*)d_in[14];
    const float* b1       = (const float*)d_in[15];
    const float* W_heads  = (const float*)d_in[16];
    const float* b_heads  = (const float*)d_in[17];
    float* out = (float*)d_out;

    float* ws = (float*)d_ws;
    // workspace layout (floats), offsets 64-aligned
    float* agg0 = ws + 0;                       // 150000
    float* H    = ws + 150016;                  // 6,400,000
    float* P    = ws + 6550016;                 // 25,600,000
    float* agg  = ws + 32150016;                // 6,400,000
    unsigned short* Bfrag = (unsigned short*)(ws + 38550016); // 262144 ushort = 131072 floats (old Wcat slot)
    float* gsum = ws + 38681088;                // 32768
    float* gcnt = ws + 38713856;                // 256
    float2* WL2 = (float2*)(ws + 38714112);     // 2 layers x 32 x 128 float2

    // conv1
    hipMemsetAsync(agg0, 0, (size_t)N_NODES * 3 * sizeof(float), stream);
    conv1_kernel<<<(N_EDGES + 255)/256, 256, 0, stream>>>(x, ei, EA, Wf1, bf1, Ws1, bs1, agg0);
    // proj
    proj_kernel<<<(N_NODES*HIDDEN + 255)/256, 256, 0, stream>>>(x, agg0, Wp, bp, H);
    // repack weights for both layers
    repack_frag_kernel<<<(2*32*4*64 + 255)/256, 256, 0, stream>>>(Wf_convs, Ws_convs, Bfrag);
    repack_edge_kernel<<<(2*32*128 + 255)/256, 256, 0, stream>>>(Wf_convs, Ws_convs, WL2);

    for (int l = 0; l < 2; ++l) {
        const unsigned short* Bfrag_l = Bfrag + (size_t)l * 32*4*64*8;
        const float2* WL2_l = WL2 + (size_t)l * 32 * 128;
        const float* bfl = bf_convs + (size_t)l * HIDDEN;
        const float* bsl = bs_convs + (size_t)l * HIDDEN;
        // P = H @ Wcat_l  (50000 x 128 x 512) via bf16 MFMA
        dim3 ggrid(2, (N_NODES + 63)/64);
        gemm_mfma<<<ggrid, 256, 0, stream>>>(H, Bfrag_l, P);
        // agg = 0; edge messages
        hipMemsetAsync(agg, 0, (size_t)N_NODES * HIDDEN * sizeof(float), stream);
        edge_kernel<<<2048, 256, 0, stream>>>(P, EA, ei, WL2_l, bfl, bsl, agg);
        // H = relu(H + agg)
        update_kernel<<<(N_NODES*HIDDEN + 255)/256, 256, 0, stream>>>(H, agg);
    }

    // pool + heads
    hipMemsetAsync(gsum, 0, (size_t)(NUM_GRAPHS * HIDDEN + NUM_GRAPHS) * sizeof(float), stream);
    pool_kernel<<<(N_NODES + 127)/128, 128, 0, stream>>>(H, batch, gsum, gcnt);
    head_kernel<<<NUM_GRAPHS, 128, 0, stream>>>(gsum, gcnt, W1, b1, W_heads, b_heads, out);
}

// Round 7
// 1132.682 us; speedup vs baseline: 2.0492x; 1.0963x over previous
//
#include <hip/hip_runtime.h>
#include <hip/hip_bf16.h>
#include <math.h>

// Problem constants (fixed by the reference)
#define N_NODES 50000
#define N_EDGES 800000
#define NODE_DIM 3
#define EDGE_DIM 32
#define HIDDEN 128
#define NUM_GRAPHS 256
#define ZIN (2*HIDDEN + EDGE_DIM)   // 288

typedef __attribute__((ext_vector_type(8))) short short8;
typedef __attribute__((ext_vector_type(4))) float f32x4;

// fp32 -> bf16 (RNE), finite inputs
__device__ __forceinline__ unsigned short f2bf(float x) {
    unsigned u = __float_as_uint(x);
    u += 0x7FFFu + ((u >> 16) & 1u);
    return (unsigned short)(u >> 16);
}
// low/high bf16 of a packed uint -> fp32
__device__ __forceinline__ float bf_lo(unsigned u) { return __uint_as_float(u << 16); }
__device__ __forceinline__ float bf_hi(unsigned u) { return __uint_as_float(u & 0xFFFF0000u); }

// ---------------------------------------------------------------------------
// conv1: CGConv on 3-dim features. One thread per edge.
// ---------------------------------------------------------------------------
__global__ __launch_bounds__(256) void conv1_kernel(
    const float* __restrict__ x, const int* __restrict__ ei,
    const float* __restrict__ EA,
    const float* __restrict__ Wf1, const float* __restrict__ bf1,
    const float* __restrict__ Ws1, const float* __restrict__ bs1,
    float* __restrict__ agg0)
{
    __shared__ float WfL[38*3], WsL[38*3], bfL[3], bsL[3];
    if (threadIdx.x < 114) {
        WfL[threadIdx.x] = Wf1[threadIdx.x];
        WsL[threadIdx.x] = Ws1[threadIdx.x];
    }
    if (threadIdx.x < 3) { bfL[threadIdx.x] = bf1[threadIdx.x]; bsL[threadIdx.x] = bs1[threadIdx.x]; }
    __syncthreads();

    int e = blockIdx.x * 256 + threadIdx.x;
    if (e >= N_EDGES) return;
    int s = ei[e];
    int d = ei[N_EDGES + e];

    float z[38];
    z[0] = x[d*3+0]; z[1] = x[d*3+1]; z[2] = x[d*3+2];
    z[3] = x[s*3+0]; z[4] = x[s*3+1]; z[5] = x[s*3+2];
    const float4* ep = (const float4*)(EA + (size_t)e * EDGE_DIM);
    #pragma unroll
    for (int q = 0; q < 8; ++q) {
        float4 v = ep[q];
        z[6+4*q+0] = v.x; z[6+4*q+1] = v.y; z[6+4*q+2] = v.z; z[6+4*q+3] = v.w;
    }
    float f[3], g[3];
    #pragma unroll
    for (int c = 0; c < 3; ++c) { f[c] = bfL[c]; g[c] = bsL[c]; }
    #pragma unroll
    for (int j = 0; j < 38; ++j) {
        #pragma unroll
        for (int c = 0; c < 3; ++c) {
            f[c] += z[j] * WfL[j*3+c];
            g[c] += z[j] * WsL[j*3+c];
        }
    }
    #pragma unroll
    for (int c = 0; c < 3; ++c) {
        float sig = __builtin_amdgcn_rcpf(1.0f + __expf(-f[c]));
        float sp  = fmaxf(g[c], 0.0f) + __logf(1.0f + __expf(-fabsf(g[c])));
        atomicAdd(agg0 + (size_t)d*3 + c, sig * sp);
    }
}

// ---------------------------------------------------------------------------
// proj: H[n][c] = relu(bp[c] + sum_j (x[n][j]+agg0[n][j]) * Wp[j][c])
// ---------------------------------------------------------------------------
__global__ __launch_bounds__(256) void proj_kernel(
    const float* __restrict__ x, const float* __restrict__ agg0,
    const float* __restrict__ Wp, const float* __restrict__ bp,
    float* __restrict__ H)
{
    int idx = blockIdx.x * 256 + threadIdx.x;
    if (idx >= N_NODES * HIDDEN) return;
    int n = idx >> 7, c = idx & 127;
    float h0 = x[n*3+0] + agg0[n*3+0];
    float h1 = x[n*3+1] + agg0[n*3+1];
    float h2 = x[n*3+2] + agg0[n*3+2];
    float v = bp[c] + h0*Wp[0*128+c] + h1*Wp[1*128+c] + h2*Wp[2*128+c];
    H[idx] = fmaxf(v, 0.0f);
}

// ---------------------------------------------------------------------------
// Repack node-path weights into MFMA B-fragment layout (bf16).
// Logical Wcat (128 x 512) columns: n=2c+t in [0,256) -> (dst, t=0:Wf,t=1:Ws);
// n-256=2c+t in [256,512) -> (src).
// Bfrag[l][ntile 0..31][kc 0..3][lane 0..63][j 0..7] =
//   Wcat[k = kc*32 + (lane>>4)*8 + j][n = ntile*16 + (lane&15)].
// (Validated in R6: absmax 0.0625 with this layout.)
// ---------------------------------------------------------------------------
__global__ __launch_bounds__(256) void repack_frag_kernel(
    const float* __restrict__ Wf, const float* __restrict__ Ws,
    unsigned short* __restrict__ Bfrag)
{
    int idx = blockIdx.x * 256 + threadIdx.x;   // 2*32*4*64 = 16384
    if (idx >= 2*32*4*64) return;
    int lane = idx & 63;
    int kc   = (idx >> 6) & 3;
    int nt   = (idx >> 8) & 31;
    int l    = idx >> 13;
    const float* wf  = Wf + (size_t)l * ZIN * HIDDEN;
    const float* wsp = Ws + (size_t)l * ZIN * HIDDEN;
    int n = nt*16 + (lane & 15);
    int half = n >> 8;           // 0 = dst rows, 1 = src rows
    int within = n & 255;
    int cc = within >> 1;
    int t = within & 1;
    const float* W = t ? wsp : wf;
    unsigned short vals[8];
    #pragma unroll
    for (int j = 0; j < 8; ++j) {
        int k = kc*32 + (lane >> 4)*8 + j;
        vals[j] = f2bf(W[(size_t)(half*128 + k)*128 + cc]);
    }
    *(short8*)(Bfrag + (size_t)idx * 8) = *(short8*)vals;
}

// ---------------------------------------------------------------------------
// Repack EDGE-path weights (rows 256..287 of Wf/Ws) into B-frags, SPLIT cols:
// BE[l][nt 0..15][lane][j]: nt<8 -> Wf col c=nt*16+(lane&15); nt>=8 -> Ws col
// c=(nt-8)*16+(lane&15); k = (lane>>4)*8+j (K=32, single chunk).
// ---------------------------------------------------------------------------
__global__ __launch_bounds__(256) void repack_edge_frag_kernel(
    const float* __restrict__ Wf, const float* __restrict__ Ws,
    unsigned short* __restrict__ BE)
{
    int idx = blockIdx.x * 256 + threadIdx.x;   // 2*16*64 = 2048
    if (idx >= 2*16*64) return;
    int lane = idx & 63;
    int nt   = (idx >> 6) & 15;
    int l    = idx >> 10;
    const float* W = ((nt & 8) ? Ws : Wf) + (size_t)l * ZIN * HIDDEN + 256*128;
    int c = (nt & 7)*16 + (lane & 15);
    unsigned short vals[8];
    #pragma unroll
    for (int j = 0; j < 8; ++j) {
        int k = (lane >> 4)*8 + j;
        vals[j] = f2bf(W[(size_t)k*128 + c]);
    }
    *(short8*)(BE + (size_t)idx * 8) = *(short8*)vals;
}

// ---------------------------------------------------------------------------
// Node MFMA GEMM: Pb(50000x512 bf16) = H(50000x128 fp32->bf16) @ Wcat + bias.
// Biases (bf,bs) folded into the accumulator init on the dst half (cols<256),
// so the edge kernel needs no bias loads. Layout validated in R6.
// ---------------------------------------------------------------------------
__global__ __launch_bounds__(256) void gemm_mfma(
    const float* __restrict__ H, const unsigned short* __restrict__ Bfrag,
    const float* __restrict__ bf, const float* __restrict__ bs,
    unsigned short* __restrict__ Pb)
{
    const int lane = threadIdx.x & 63;
    const int wave = threadIdx.x >> 6;
    const int m    = lane & 15;
    const int quad = lane >> 4;
    const int rowA = blockIdx.y * 64 + wave * 16 + m;   // OOB reads land in ws (safe); stores masked
    const int colBase = blockIdx.x * 256;

    const float* hrow = H + (size_t)rowA * 128;
    short8 a[4];
    #pragma unroll
    for (int kc = 0; kc < 4; ++kc) {
        float4 v0 = *(const float4*)(hrow + kc*32 + quad*8);
        float4 v1 = *(const float4*)(hrow + kc*32 + quad*8 + 4);
        unsigned short t[8];
        t[0]=f2bf(v0.x); t[1]=f2bf(v0.y); t[2]=f2bf(v0.z); t[3]=f2bf(v0.w);
        t[4]=f2bf(v1.x); t[5]=f2bf(v1.y); t[6]=f2bf(v1.z); t[7]=f2bf(v1.w);
        a[kc] = *(short8*)t;
    }

    f32x4 acc[16];
    #pragma unroll
    for (int nt = 0; nt < 16; ++nt) {
        float bias = 0.0f;
        if (colBase == 0) {                    // dst half: fold biases in
            int col = nt*16 + m;
            bias = (col & 1) ? bs[col >> 1] : bf[col >> 1];
        }
        acc[nt] = (f32x4){bias, bias, bias, bias};
    }

    #pragma unroll
    for (int nt = 0; nt < 16; ++nt) {
        int ntg = (colBase >> 4) + nt;
        const unsigned short* bp = Bfrag + ((size_t)(ntg*4) * 64 + lane) * 8;
        #pragma unroll
        for (int kc = 0; kc < 4; ++kc) {
            short8 b = *(const short8*)(bp + (size_t)kc * 64 * 8);
            acc[nt] = __builtin_amdgcn_mfma_f32_16x16x32_bf16(a[kc], b, acc[nt], 0, 0, 0);
        }
    }

    const int rowC = blockIdx.y * 64 + wave * 16 + quad * 4;
    #pragma unroll
    for (int nt = 0; nt < 16; ++nt) {
        int col = colBase + nt*16 + m;
        #pragma unroll
        for (int r = 0; r < 4; ++r) {
            int row = rowC + r;
            if (row < N_NODES) Pb[(size_t)row * 512 + col] = f2bf(acc[nt][r]);
        }
    }
}

// ---------------------------------------------------------------------------
// Fused edge kernel, v6 (MFMA edge-dot).
// One wave processes 16 whole edges: A-frag = 16 EA rows (K=32 = one MFMA),
// B-frags = edge weights from LDS (split f/s tile layout). D layout gives
// lane -> (edge = quad*4+r, channel = nt*16+m). Per lane: 32 cells of
// P-gather (bf16 pairs, biases pre-folded) + sigmoid*softplus + atomicAdd.
// Replaces 128 VALU FMAs + 64 LDS reads per thread with 2 MFMAs/tile-pair.
// ---------------------------------------------------------------------------
__global__ __launch_bounds__(256) void edge_kernel(
    const unsigned short* __restrict__ Pb, const float* __restrict__ EA,
    const int* __restrict__ ei,
    const unsigned short* __restrict__ BE,   // 16 nt x 64 lane x 8 bf16
    float* __restrict__ agg)
{
    __shared__ unsigned short BL[16*64*8];   // 16 KB
    for (int i = threadIdx.x; i < 1024; i += 256)
        ((short8*)BL)[i] = ((const short8*)BE)[i];
    __syncthreads();

    const int lane = threadIdx.x & 63;
    const int wave = threadIdx.x >> 6;
    const int m    = lane & 15;
    const int quad = lane >> 4;
    const int e0   = blockIdx.x * 64 + wave * 16;   // 800000 % 64 == 0

    // A-frag: EA[e0+m][quad*8 .. +7] -> bf16
    const float* ea = EA + (size_t)(e0 + m) * EDGE_DIM + quad*8;
    float4 v0 = *(const float4*)ea;
    float4 v1 = *(const float4*)(ea + 4);
    unsigned short t[8];
    t[0]=f2bf(v0.x); t[1]=f2bf(v0.y); t[2]=f2bf(v0.z); t[3]=f2bf(v0.w);
    t[4]=f2bf(v1.x); t[5]=f2bf(v1.y); t[6]=f2bf(v1.z); t[7]=f2bf(v1.w);
    short8 a = *(short8*)t;

    // Edge endpoints for this lane's 4 edges (quad*4+r)
    const int* srcA = ei;
    const int* dstA = ei + N_EDGES;
    int dr[4], sr[4];
    #pragma unroll
    for (int r = 0; r < 4; ++r) {
        dr[r] = dstA[e0 + quad*4 + r];
        sr[r] = srcA[e0 + quad*4 + r];
    }

    const f32x4 zero = (f32x4){0.f, 0.f, 0.f, 0.f};
    #pragma unroll
    for (int nt = 0; nt < 8; ++nt) {
        short8 bF = *(const short8*)(BL + ((size_t)(nt     *64 + lane)) * 8);
        short8 bS = *(const short8*)(BL + ((size_t)((nt+8) *64 + lane)) * 8);
        f32x4 qf = __builtin_amdgcn_mfma_f32_16x16x32_bf16(a, bF, zero, 0, 0, 0);
        f32x4 qs = __builtin_amdgcn_mfma_f32_16x16x32_bf16(a, bS, zero, 0, 0, 0);
        int c = nt*16 + m;                       // channel 0..127
        #pragma unroll
        for (int r = 0; r < 4; ++r) {
            unsigned pd = *(const unsigned*)(Pb + (size_t)dr[r]*512 + 2*c);
            unsigned ps = *(const unsigned*)(Pb + (size_t)sr[r]*512 + 256 + 2*c);
            float f = bf_lo(pd) + bf_lo(ps) + qf[r];
            float g = bf_hi(pd) + bf_hi(ps) + qs[r];
            float sig = __builtin_amdgcn_rcpf(1.0f + __expf(-f));
            float sp  = fmaxf(g, 0.0f) + __logf(1.0f + __expf(-fabsf(g)));
            atomicAdd(agg + (size_t)dr[r] * HIDDEN + c, sig * sp);
        }
    }
}

// ---------------------------------------------------------------------------
// H = relu(H + agg)
// ---------------------------------------------------------------------------
__global__ __launch_bounds__(256) void update_kernel(
    float* __restrict__ H, const float* __restrict__ agg)
{
    int idx = blockIdx.x * 256 + threadIdx.x;
    if (idx >= N_NODES * HIDDEN) return;
    H[idx] = fmaxf(H[idx] + agg[idx], 0.0f);
}

// ---------------------------------------------------------------------------
// Pool: per-graph sums + counts (batch sorted; run-length then atomic).
// ---------------------------------------------------------------------------
__global__ __launch_bounds__(128) void pool_kernel(
    const float* __restrict__ H, const int* __restrict__ batch,
    float* __restrict__ gsum, float* __restrict__ gcnt)
{
    const int c = threadIdx.x;
    const int n0 = blockIdx.x * 128;
    float acc = 0.0f;
    int cur = -1;
    for (int i = 0; i < 128; ++i) {
        int n = n0 + i;
        if (n >= N_NODES) break;
        int g = batch[n];
        if (g != cur) {
            if (cur >= 0) atomicAdd(gsum + (size_t)cur * HIDDEN + c, acc);
            cur = g; acc = 0.0f;
        }
        acc += H[(size_t)n * HIDDEN + c];
    }
    if (cur >= 0) atomicAdd(gsum + (size_t)cur * HIDDEN + c, acc);

    if (c == 0) {
        int curg = -1; float run = 0.0f;
        for (int i = 0; i < 128; ++i) {
            int n = n0 + i;
            if (n >= N_NODES) break;
            int g = batch[n];
            if (g != curg) {
                if (curg >= 0) atomicAdd(gcnt + curg, run);
                curg = g; run = 0.0f;
            }
            run += 1.0f;
        }
        if (curg >= 0) atomicAdd(gcnt + curg, run);
    }
}

// ---------------------------------------------------------------------------
// Final MLP: g = relu((gsum/cnt) @ W1 + b1); out = g @ Wh^T + bh
// ---------------------------------------------------------------------------
__global__ __launch_bounds__(128) void head_kernel(
    const float* __restrict__ gsum, const float* __restrict__ gcnt,
    const float* __restrict__ W1, const float* __restrict__ b1,
    const float* __restrict__ Wh, const float* __restrict__ bh,
    float* __restrict__ out)
{
    __shared__ float gavg[128];
    __shared__ float g1[128];
    const int g = blockIdx.x, c = threadIdx.x;
    float cnt = fmaxf(gcnt[g], 1.0f);
    gavg[c] = gsum[(size_t)g * HIDDEN + c] / cnt;
    __syncthreads();
    float acc = b1[c];
    for (int k = 0; k < 128; ++k) acc += gavg[k] * W1[k*128 + c];
    g1[c] = fmaxf(acc, 0.0f);
    __syncthreads();
    if (c < 5) {
        float o = bh[c];
        for (int k = 0; k < 128; ++k) o += g1[k] * Wh[c*128 + k];
        out[(size_t)g * 5 + c] = o;
    }
}

// ---------------------------------------------------------------------------
// Launch
// ---------------------------------------------------------------------------
extern "C" void kernel_launch(void* const* d_in, const int* in_sizes, int n_in,
                              void* d_out, int out_size, void* d_ws, size_t ws_size,
                              hipStream_t stream) {
    const float* x        = (const float*)d_in[0];
    const int*   ei       = (const int*)  d_in[1];
    const float* EA       = (const float*)d_in[2];
    const int*   batch    = (const int*)  d_in[3];
    const float* Wf1      = (const float*)d_in[4];
    const float* bf1      = (const float*)d_in[5];
    const float* Ws1      = (const float*)d_in[6];
    const float* bs1      = (const float*)d_in[7];
    const float* Wp       = (const float*)d_in[8];
    const float* bp       = (const float*)d_in[9];
    const float* Wf_convs = (const float*)d_in[10];
    const float* bf_convs = (const float*)d_in[11];
    const float* Ws_convs = (const float*)d_in[12];
    const float* bs_convs = (const float*)d_in[13];
    const float* W1       = (const float*)d_in[14];
    const float* b1       = (const float*)d_in[15];
    const float* W_heads  = (const float*)d_in[16];
    const float* b_heads  = (const float*)d_in[17];
    float* out = (float*)d_out;

    float* ws = (float*)d_ws;
    // workspace layout (floats), ~103 MB total
    float* agg0 = ws + 0;                               // 150000
    float* H    = ws + 150016;                          // 6,400,000
    unsigned short* Pb = (unsigned short*)(ws + 6550016);   // 50000*512 ushort = 12.8M floats
    float* agg  = ws + 19350016;                        // 6,400,000
    unsigned short* Bfrag = (unsigned short*)(ws + 25750016); // 2*32*4*64*8 ushort = 65536 floats
    unsigned short* BE    = (unsigned short*)(ws + 25815552); // 2*16*64*8 ushort = 8192 floats
    float* gsum = ws + 25823744;                        // 32768
    float* gcnt = ws + 25856512;                        // 256

    // conv1
    hipMemsetAsync(agg0, 0, (size_t)N_NODES * 3 * sizeof(float), stream);
    conv1_kernel<<<(N_EDGES + 255)/256, 256, 0, stream>>>(x, ei, EA, Wf1, bf1, Ws1, bs1, agg0);
    // proj
    proj_kernel<<<(N_NODES*HIDDEN + 255)/256, 256, 0, stream>>>(x, agg0, Wp, bp, H);
    // repack weights for both layers
    repack_frag_kernel<<<(2*32*4*64 + 255)/256, 256, 0, stream>>>(Wf_convs, Ws_convs, Bfrag);
    repack_edge_frag_kernel<<<(2*16*64 + 255)/256, 256, 0, stream>>>(Wf_convs, Ws_convs, BE);

    for (int l = 0; l < 2; ++l) {
        const unsigned short* Bfrag_l = Bfrag + (size_t)l * 32*4*64*8;
        const unsigned short* BE_l    = BE    + (size_t)l * 16*64*8;
        const float* bfl = bf_convs + (size_t)l * HIDDEN;
        const float* bsl = bs_convs + (size_t)l * HIDDEN;
        // Pb = bf16(H @ Wcat_l + bias)  (50000 x 128 x 512) via MFMA
        dim3 ggrid(2, (N_NODES + 63)/64);
        gemm_mfma<<<ggrid, 256, 0, stream>>>(H, Bfrag_l, bfl, bsl, Pb);
        // agg = 0; edge messages (MFMA edge-dot, 64 edges/block)
        hipMemsetAsync(agg, 0, (size_t)N_NODES * HIDDEN * sizeof(float), stream);
        edge_kernel<<<N_EDGES/64, 256, 0, stream>>>(Pb, EA, ei, BE_l, agg);
        // H = relu(H + agg)
        update_kernel<<<(N_NODES*HIDDEN + 255)/256, 256, 0, stream>>>(H, agg);
    }

    // pool + heads
    hipMemsetAsync(gsum, 0, (size_t)(NUM_GRAPHS * HIDDEN + NUM_GRAPHS) * sizeof(float), stream);
    pool_kernel<<<(N_NODES + 127)/128, 128, 0, stream>>>(H, batch, gsum, gcnt);
    head_kernel<<<NUM_GRAPHS, 128, 0, stream>>>(gsum, gcnt, W1, b1, W_heads, b_heads, out);
}

// Round 8
// 857.335 us; speedup vs baseline: 2.7073x; 1.3212x over previous
//
#include <hip/hip_runtime.h>
#include <hip/hip_bf16.h>
#include <math.h>

// Problem constants (fixed by the reference)
#define N_NODES 50000
#define N_EDGES 800000
#define NODE_DIM 3
#define EDGE_DIM 32
#define HIDDEN 128
#define NUM_GRAPHS 256
#define ZIN (2*HIDDEN + EDGE_DIM)   // 288
#define NPAD 50176                  // 196 * 256 (padded node count for scan)

typedef __attribute__((ext_vector_type(8))) short short8;
typedef __attribute__((ext_vector_type(4))) float f32x4;

// fp32 -> bf16 (RNE), finite inputs
__device__ __forceinline__ unsigned short f2bf(float x) {
    unsigned u = __float_as_uint(x);
    u += 0x7FFFu + ((u >> 16) & 1u);
    return (unsigned short)(u >> 16);
}
// low/high bf16 of a packed uint -> fp32
__device__ __forceinline__ float bf_lo(unsigned u) { return __uint_as_float(u << 16); }
__device__ __forceinline__ float bf_hi(unsigned u) { return __uint_as_float(u & 0xFFFF0000u); }

// ---------------------------------------------------------------------------
// conv1: CGConv on 3-dim features. One thread per edge.
// ---------------------------------------------------------------------------
__global__ __launch_bounds__(256) void conv1_kernel(
    const float* __restrict__ x, const int* __restrict__ ei,
    const float* __restrict__ EA,
    const float* __restrict__ Wf1, const float* __restrict__ bf1,
    const float* __restrict__ Ws1, const float* __restrict__ bs1,
    float* __restrict__ agg0)
{
    __shared__ float WfL[38*3], WsL[38*3], bfL[3], bsL[3];
    if (threadIdx.x < 114) {
        WfL[threadIdx.x] = Wf1[threadIdx.x];
        WsL[threadIdx.x] = Ws1[threadIdx.x];
    }
    if (threadIdx.x < 3) { bfL[threadIdx.x] = bf1[threadIdx.x]; bsL[threadIdx.x] = bs1[threadIdx.x]; }
    __syncthreads();

    int e = blockIdx.x * 256 + threadIdx.x;
    if (e >= N_EDGES) return;
    int s = ei[e];
    int d = ei[N_EDGES + e];

    float z[38];
    z[0] = x[d*3+0]; z[1] = x[d*3+1]; z[2] = x[d*3+2];
    z[3] = x[s*3+0]; z[4] = x[s*3+1]; z[5] = x[s*3+2];
    const float4* ep = (const float4*)(EA + (size_t)e * EDGE_DIM);
    #pragma unroll
    for (int q = 0; q < 8; ++q) {
        float4 v = ep[q];
        z[6+4*q+0] = v.x; z[6+4*q+1] = v.y; z[6+4*q+2] = v.z; z[6+4*q+3] = v.w;
    }
    float f[3], g[3];
    #pragma unroll
    for (int c = 0; c < 3; ++c) { f[c] = bfL[c]; g[c] = bsL[c]; }
    #pragma unroll
    for (int j = 0; j < 38; ++j) {
        #pragma unroll
        for (int c = 0; c < 3; ++c) {
            f[c] += z[j] * WfL[j*3+c];
            g[c] += z[j] * WsL[j*3+c];
        }
    }
    #pragma unroll
    for (int c = 0; c < 3; ++c) {
        float sig = __builtin_amdgcn_rcpf(1.0f + __expf(-f[c]));
        float sp  = fmaxf(g[c], 0.0f) + __logf(1.0f + __expf(-fabsf(g[c])));
        atomicAdd(agg0 + (size_t)d*3 + c, sig * sp);
    }
}

// ---------------------------------------------------------------------------
// proj: H[n][c] = relu(bp[c] + sum_j (x[n][j]+agg0[n][j]) * Wp[j][c])
// ---------------------------------------------------------------------------
__global__ __launch_bounds__(256) void proj_kernel(
    const float* __restrict__ x, const float* __restrict__ agg0,
    const float* __restrict__ Wp, const float* __restrict__ bp,
    float* __restrict__ H)
{
    int idx = blockIdx.x * 256 + threadIdx.x;
    if (idx >= N_NODES * HIDDEN) return;
    int n = idx >> 7, c = idx & 127;
    float h0 = x[n*3+0] + agg0[n*3+0];
    float h1 = x[n*3+1] + agg0[n*3+1];
    float h2 = x[n*3+2] + agg0[n*3+2];
    float v = bp[c] + h0*Wp[0*128+c] + h1*Wp[1*128+c] + h2*Wp[2*128+c];
    H[idx] = fmaxf(v, 0.0f);
}

// ---------------------------------------------------------------------------
// Counting sort of edges by dst: hist -> 2-level exclusive scan -> scatter.
// ---------------------------------------------------------------------------
__global__ __launch_bounds__(256) void hist_kernel(
    const int* __restrict__ ei, int* __restrict__ hist)
{
    int e = blockIdx.x * 256 + threadIdx.x;
    if (e < N_EDGES) atomicAdd(&hist[ei[N_EDGES + e]], 1);
}

// Per-block exclusive scan of hist (256 elems) -> cursor; block total -> btot.
__global__ __launch_bounds__(256) void scanA_kernel(
    const int* __restrict__ hist, int* __restrict__ cursor, int* __restrict__ btot)
{
    __shared__ int tmp[256];
    int t = threadIdx.x;
    int i = blockIdx.x * 256 + t;
    int v = hist[i];
    tmp[t] = v;
    __syncthreads();
    #pragma unroll
    for (int off = 1; off < 256; off <<= 1) {
        int y = (t >= off) ? tmp[t - off] : 0;
        __syncthreads();
        if (t >= off) tmp[t] += y;
        __syncthreads();
    }
    cursor[i] = tmp[t] - v;               // exclusive within block
    if (t == 255) btot[blockIdx.x] = tmp[t];
}

// Single block: exclusive scan of 256 block totals in place.
__global__ __launch_bounds__(256) void scanB_kernel(int* __restrict__ btot)
{
    __shared__ int tmp[256];
    int t = threadIdx.x;
    int v = btot[t];
    tmp[t] = v;
    __syncthreads();
    #pragma unroll
    for (int off = 1; off < 256; off <<= 1) {
        int y = (t >= off) ? tmp[t - off] : 0;
        __syncthreads();
        if (t >= off) tmp[t] += y;
        __syncthreads();
    }
    btot[t] = tmp[t] - v;                 // exclusive
}

__global__ __launch_bounds__(256) void scanC_kernel(
    int* __restrict__ cursor, const int* __restrict__ btot)
{
    int i = blockIdx.x * 256 + threadIdx.x;
    cursor[i] += btot[blockIdx.x];
}

// Scatter: p = bucket slot for edge e; record eid/src/dst in sorted position.
__global__ __launch_bounds__(256) void scatter_kernel(
    const int* __restrict__ ei, int* __restrict__ cursor,
    int* __restrict__ peid, int* __restrict__ psrc, int* __restrict__ pdst)
{
    int e = blockIdx.x * 256 + threadIdx.x;
    if (e >= N_EDGES) return;
    int s = ei[e];
    int d = ei[N_EDGES + e];
    int p = atomicAdd(&cursor[d], 1);
    peid[p] = e; psrc[p] = s; pdst[p] = d;
}

// ---------------------------------------------------------------------------
// Repack node-path weights into MFMA B-fragment layout (bf16).
// (Validated R6/R7: absmax 0.0625.)
// ---------------------------------------------------------------------------
__global__ __launch_bounds__(256) void repack_frag_kernel(
    const float* __restrict__ Wf, const float* __restrict__ Ws,
    unsigned short* __restrict__ Bfrag)
{
    int idx = blockIdx.x * 256 + threadIdx.x;   // 2*32*4*64 = 16384
    if (idx >= 2*32*4*64) return;
    int lane = idx & 63;
    int kc   = (idx >> 6) & 3;
    int nt   = (idx >> 8) & 31;
    int l    = idx >> 13;
    const float* wf  = Wf + (size_t)l * ZIN * HIDDEN;
    const float* wsp = Ws + (size_t)l * ZIN * HIDDEN;
    int n = nt*16 + (lane & 15);
    int half = n >> 8;
    int within = n & 255;
    int cc = within >> 1;
    int t = within & 1;
    const float* W = t ? wsp : wf;
    unsigned short vals[8];
    #pragma unroll
    for (int j = 0; j < 8; ++j) {
        int k = kc*32 + (lane >> 4)*8 + j;
        vals[j] = f2bf(W[(size_t)(half*128 + k)*128 + cc]);
    }
    *(short8*)(Bfrag + (size_t)idx * 8) = *(short8*)vals;
}

// ---------------------------------------------------------------------------
// Repack EDGE-path weights (rows 256..287) into split B-frags (validated R7).
// ---------------------------------------------------------------------------
__global__ __launch_bounds__(256) void repack_edge_frag_kernel(
    const float* __restrict__ Wf, const float* __restrict__ Ws,
    unsigned short* __restrict__ BE)
{
    int idx = blockIdx.x * 256 + threadIdx.x;   // 2*16*64 = 2048
    if (idx >= 2*16*64) return;
    int lane = idx & 63;
    int nt   = (idx >> 6) & 15;
    int l    = idx >> 10;
    const float* W = ((nt & 8) ? Ws : Wf) + (size_t)l * ZIN * HIDDEN + 256*128;
    int c = (nt & 7)*16 + (lane & 15);
    unsigned short vals[8];
    #pragma unroll
    for (int j = 0; j < 8; ++j) {
        int k = (lane >> 4)*8 + j;
        vals[j] = f2bf(W[(size_t)k*128 + c]);
    }
    *(short8*)(BE + (size_t)idx * 8) = *(short8*)vals;
}

// ---------------------------------------------------------------------------
// Node MFMA GEMM: Pb(50000x512 bf16) = H @ Wcat + bias (validated R6/R7).
// ---------------------------------------------------------------------------
__global__ __launch_bounds__(256) void gemm_mfma(
    const float* __restrict__ H, const unsigned short* __restrict__ Bfrag,
    const float* __restrict__ bf, const float* __restrict__ bs,
    unsigned short* __restrict__ Pb)
{
    const int lane = threadIdx.x & 63;
    const int wave = threadIdx.x >> 6;
    const int m    = lane & 15;
    const int quad = lane >> 4;
    const int rowA = blockIdx.y * 64 + wave * 16 + m;
    const int colBase = blockIdx.x * 256;

    const float* hrow = H + (size_t)rowA * 128;
    short8 a[4];
    #pragma unroll
    for (int kc = 0; kc < 4; ++kc) {
        float4 v0 = *(const float4*)(hrow + kc*32 + quad*8);
        float4 v1 = *(const float4*)(hrow + kc*32 + quad*8 + 4);
        unsigned short t[8];
        t[0]=f2bf(v0.x); t[1]=f2bf(v0.y); t[2]=f2bf(v0.z); t[3]=f2bf(v0.w);
        t[4]=f2bf(v1.x); t[5]=f2bf(v1.y); t[6]=f2bf(v1.z); t[7]=f2bf(v1.w);
        a[kc] = *(short8*)t;
    }

    f32x4 acc[16];
    #pragma unroll
    for (int nt = 0; nt < 16; ++nt) {
        float bias = 0.0f;
        if (colBase == 0) {
            int col = nt*16 + m;
            bias = (col & 1) ? bs[col >> 1] : bf[col >> 1];
        }
        acc[nt] = (f32x4){bias, bias, bias, bias};
    }

    #pragma unroll
    for (int nt = 0; nt < 16; ++nt) {
        int ntg = (colBase >> 4) + nt;
        const unsigned short* bp = Bfrag + ((size_t)(ntg*4) * 64 + lane) * 8;
        #pragma unroll
        for (int kc = 0; kc < 4; ++kc) {
            short8 b = *(const short8*)(bp + (size_t)kc * 64 * 8);
            acc[nt] = __builtin_amdgcn_mfma_f32_16x16x32_bf16(a[kc], b, acc[nt], 0, 0, 0);
        }
    }

    const int rowC = blockIdx.y * 64 + wave * 16 + quad * 4;
    #pragma unroll
    for (int nt = 0; nt < 16; ++nt) {
        int col = colBase + nt*16 + m;
        #pragma unroll
        for (int r = 0; r < 4; ++r) {
            int row = rowC + r;
            if (row < N_NODES) Pb[(size_t)row * 512 + col] = f2bf(acc[nt][r]);
        }
    }
}

// ---------------------------------------------------------------------------
// Fused edge kernel, v7: dst-SORTED edges + LDS segmented reduction.
// Block = 64 sorted positions. Per wave: 16 edges via MFMA edge-dot (as R7),
// messages -> LDS (stride 132: 2-way bank alias = free). Then 128 threads
// run-length accumulate the sorted 64 edges per channel: ~1 atomic per
// (dst-run, channel) instead of per (edge, channel) -> ~10x fewer atomics.
// dst-half Pb gathers hit L1 within runs.
// ---------------------------------------------------------------------------
__global__ __launch_bounds__(256) void edge_kernel(
    const unsigned short* __restrict__ Pb, const float* __restrict__ EA,
    const int* __restrict__ peid, const int* __restrict__ psrc,
    const int* __restrict__ pdst,
    const unsigned short* __restrict__ BE,
    float* __restrict__ agg)
{
    __shared__ unsigned short BL[16*64*8];   // 16 KB
    __shared__ float msgL[64*132];           // 33.8 KB, stride 132 vs banks
    __shared__ int pdL[64];

    for (int i = threadIdx.x; i < 1024; i += 256)
        ((short8*)BL)[i] = ((const short8*)BE)[i];
    if (threadIdx.x < 64) pdL[threadIdx.x] = pdst[blockIdx.x*64 + threadIdx.x];

    const int lane = threadIdx.x & 63;
    const int wave = threadIdx.x >> 6;
    const int m    = lane & 15;
    const int quad = lane >> 4;
    const int p0   = blockIdx.x * 64 + wave * 16;   // 800000 % 64 == 0

    // A-frag: EA row of this lane's edge (sorted order -> random row, 128B granule)
    int eid = peid[p0 + m];
    const float* ea = EA + (size_t)eid * EDGE_DIM + quad*8;
    float4 v0 = *(const float4*)ea;
    float4 v1 = *(const float4*)(ea + 4);
    unsigned short t[8];
    t[0]=f2bf(v0.x); t[1]=f2bf(v0.y); t[2]=f2bf(v0.z); t[3]=f2bf(v0.w);
    t[4]=f2bf(v1.x); t[5]=f2bf(v1.y); t[6]=f2bf(v1.z); t[7]=f2bf(v1.w);
    short8 a = *(short8*)t;

    int dr[4], sr[4];
    #pragma unroll
    for (int r = 0; r < 4; ++r) {
        dr[r] = pdst[p0 + quad*4 + r];
        sr[r] = psrc[p0 + quad*4 + r];
    }

    __syncthreads();   // BL + pdL ready

    const f32x4 zero = (f32x4){0.f, 0.f, 0.f, 0.f};
    #pragma unroll
    for (int nt = 0; nt < 8; ++nt) {
        short8 bF = *(const short8*)(BL + ((size_t)(nt     *64 + lane)) * 8);
        short8 bS = *(const short8*)(BL + ((size_t)((nt+8) *64 + lane)) * 8);
        f32x4 qf = __builtin_amdgcn_mfma_f32_16x16x32_bf16(a, bF, zero, 0, 0, 0);
        f32x4 qs = __builtin_amdgcn_mfma_f32_16x16x32_bf16(a, bS, zero, 0, 0, 0);
        int c = nt*16 + m;
        #pragma unroll
        for (int r = 0; r < 4; ++r) {
            unsigned pd = *(const unsigned*)(Pb + (size_t)dr[r]*512 + 2*c);
            unsigned ps = *(const unsigned*)(Pb + (size_t)sr[r]*512 + 256 + 2*c);
            float f = bf_lo(pd) + bf_lo(ps) + qf[r];
            float g = bf_hi(pd) + bf_hi(ps) + qs[r];
            float sig = __builtin_amdgcn_rcpf(1.0f + __expf(-f));
            float sp  = fmaxf(g, 0.0f) + __logf(1.0f + __expf(-fabsf(g)));
            msgL[(wave*16 + quad*4 + r)*132 + c] = sig * sp;
        }
    }
    __syncthreads();

    // Segmented reduction: thread -> (channel c2, 32-edge segment)
    const int c2  = threadIdx.x & 127;
    const int seg = threadIdx.x >> 7;
    const int base = seg * 32;
    float acc = 0.0f;
    int cur = pdL[base];
    #pragma unroll 4
    for (int i = 0; i < 32; ++i) {
        int dd = pdL[base + i];
        float v = msgL[(base + i)*132 + c2];
        if (dd != cur) {
            atomicAdd(&agg[(size_t)cur * HIDDEN + c2], acc);
            acc = 0.0f; cur = dd;
        }
        acc += v;
    }
    atomicAdd(&agg[(size_t)cur * HIDDEN + c2], acc);
}

// ---------------------------------------------------------------------------
// H = relu(H + agg)
// ---------------------------------------------------------------------------
__global__ __launch_bounds__(256) void update_kernel(
    float* __restrict__ H, const float* __restrict__ agg)
{
    int idx = blockIdx.x * 256 + threadIdx.x;
    if (idx >= N_NODES * HIDDEN) return;
    H[idx] = fmaxf(H[idx] + agg[idx], 0.0f);
}

// ---------------------------------------------------------------------------
// Pool: per-graph sums + counts (batch sorted; run-length then atomic).
// ---------------------------------------------------------------------------
__global__ __launch_bounds__(128) void pool_kernel(
    const float* __restrict__ H, const int* __restrict__ batch,
    float* __restrict__ gsum, float* __restrict__ gcnt)
{
    const int c = threadIdx.x;
    const int n0 = blockIdx.x * 128;
    float acc = 0.0f;
    int cur = -1;
    for (int i = 0; i < 128; ++i) {
        int n = n0 + i;
        if (n >= N_NODES) break;
        int g = batch[n];
        if (g != cur) {
            if (cur >= 0) atomicAdd(gsum + (size_t)cur * HIDDEN + c, acc);
            cur = g; acc = 0.0f;
        }
        acc += H[(size_t)n * HIDDEN + c];
    }
    if (cur >= 0) atomicAdd(gsum + (size_t)cur * HIDDEN + c, acc);

    if (c == 0) {
        int curg = -1; float run = 0.0f;
        for (int i = 0; i < 128; ++i) {
            int n = n0 + i;
            if (n >= N_NODES) break;
            int g = batch[n];
            if (g != curg) {
                if (curg >= 0) atomicAdd(gcnt + curg, run);
                curg = g; run = 0.0f;
            }
            run += 1.0f;
        }
        if (curg >= 0) atomicAdd(gcnt + curg, run);
    }
}

// ---------------------------------------------------------------------------
// Final MLP: g = relu((gsum/cnt) @ W1 + b1); out = g @ Wh^T + bh
// ---------------------------------------------------------------------------
__global__ __launch_bounds__(128) void head_kernel(
    const float* __restrict__ gsum, const float* __restrict__ gcnt,
    const float* __restrict__ W1, const float* __restrict__ b1,
    const float* __restrict__ Wh, const float* __restrict__ bh,
    float* __restrict__ out)
{
    __shared__ float gavg[128];
    __shared__ float g1[128];
    const int g = blockIdx.x, c = threadIdx.x;
    float cnt = fmaxf(gcnt[g], 1.0f);
    gavg[c] = gsum[(size_t)g * HIDDEN + c] / cnt;
    __syncthreads();
    float acc = b1[c];
    for (int k = 0; k < 128; ++k) acc += gavg[k] * W1[k*128 + c];
    g1[c] = fmaxf(acc, 0.0f);
    __syncthreads();
    if (c < 5) {
        float o = bh[c];
        for (int k = 0; k < 128; ++k) o += g1[k] * Wh[c*128 + k];
        out[(size_t)g * 5 + c] = o;
    }
}

// ---------------------------------------------------------------------------
// Launch
// ---------------------------------------------------------------------------
extern "C" void kernel_launch(void* const* d_in, const int* in_sizes, int n_in,
                              void* d_out, int out_size, void* d_ws, size_t ws_size,
                              hipStream_t stream) {
    const float* x        = (const float*)d_in[0];
    const int*   ei       = (const int*)  d_in[1];
    const float* EA       = (const float*)d_in[2];
    const int*   batch    = (const int*)  d_in[3];
    const float* Wf1      = (const float*)d_in[4];
    const float* bf1      = (const float*)d_in[5];
    const float* Ws1      = (const float*)d_in[6];
    const float* bs1      = (const float*)d_in[7];
    const float* Wp       = (const float*)d_in[8];
    const float* bp       = (const float*)d_in[9];
    const float* Wf_convs = (const float*)d_in[10];
    const float* bf_convs = (const float*)d_in[11];
    const float* Ws_convs = (const float*)d_in[12];
    const float* bs_convs = (const float*)d_in[13];
    const float* W1       = (const float*)d_in[14];
    const float* b1       = (const float*)d_in[15];
    const float* W_heads  = (const float*)d_in[16];
    const float* b_heads  = (const float*)d_in[17];
    float* out = (float*)d_out;

    float* ws = (float*)d_ws;
    // workspace layout (float units), ~113 MB total
    float* agg0 = ws + 0;                                   // 150000
    float* H    = ws + 150016;                              // 6,400,000
    unsigned short* Pb = (unsigned short*)(ws + 6550016);   // 25.6M ushort
    float* agg  = ws + 19350016;                            // 6,400,000
    unsigned short* Bfrag = (unsigned short*)(ws + 25750016); // 131072 ushort
    unsigned short* BE    = (unsigned short*)(ws + 25815552); // 16384 ushort
    float* gsum = ws + 25823744;                            // 32768
    float* gcnt = ws + 25856512;                            // 256 (+pad)
    int* hist   = (int*)(ws + 25857024);                    // NPAD
    int* cursor = (int*)(ws + 25907200);                    // NPAD
    int* btot   = (int*)(ws + 25957376);                    // 256
    int* peid   = (int*)(ws + 25957632);                    // 800000
    int* psrc   = (int*)(ws + 26757632);                    // 800000
    int* pdst   = (int*)(ws + 27557632);                    // 800000

    // ---- edge sort by dst (graph is static; rebuilt every launch) ----
    hipMemsetAsync(hist, 0, (size_t)(2*NPAD + 256) * sizeof(int), stream); // hist+cursor+btot
    hist_kernel<<<(N_EDGES + 255)/256, 256, 0, stream>>>(ei, hist);
    scanA_kernel<<<NPAD/256, 256, 0, stream>>>(hist, cursor, btot);
    scanB_kernel<<<1, 256, 0, stream>>>(btot);
    scanC_kernel<<<NPAD/256, 256, 0, stream>>>(cursor, btot);
    scatter_kernel<<<(N_EDGES + 255)/256, 256, 0, stream>>>(ei, cursor, peid, psrc, pdst);

    // conv1 + proj
    hipMemsetAsync(agg0, 0, (size_t)N_NODES * 3 * sizeof(float), stream);
    conv1_kernel<<<(N_EDGES + 255)/256, 256, 0, stream>>>(x, ei, EA, Wf1, bf1, Ws1, bs1, agg0);
    proj_kernel<<<(N_NODES*HIDDEN + 255)/256, 256, 0, stream>>>(x, agg0, Wp, bp, H);
    // repack weights for both layers
    repack_frag_kernel<<<(2*32*4*64 + 255)/256, 256, 0, stream>>>(Wf_convs, Ws_convs, Bfrag);
    repack_edge_frag_kernel<<<(2*16*64 + 255)/256, 256, 0, stream>>>(Wf_convs, Ws_convs, BE);

    for (int l = 0; l < 2; ++l) {
        const unsigned short* Bfrag_l = Bfrag + (size_t)l * 32*4*64*8;
        const unsigned short* BE_l    = BE    + (size_t)l * 16*64*8;
        const float* bfl = bf_convs + (size_t)l * HIDDEN;
        const float* bsl = bs_convs + (size_t)l * HIDDEN;
        // Pb = bf16(H @ Wcat_l + bias) via MFMA
        dim3 ggrid(2, (N_NODES + 63)/64);
        gemm_mfma<<<ggrid, 256, 0, stream>>>(H, Bfrag_l, bfl, bsl, Pb);
        // agg = 0; sorted edge messages + segmented reduce
        hipMemsetAsync(agg, 0, (size_t)N_NODES * HIDDEN * sizeof(float), stream);
        edge_kernel<<<N_EDGES/64, 256, 0, stream>>>(Pb, EA, peid, psrc, pdst, BE_l, agg);
        // H = relu(H + agg)
        update_kernel<<<(N_NODES*HIDDEN + 255)/256, 256, 0, stream>>>(H, agg);
    }

    // pool + heads
    hipMemsetAsync(gsum, 0, (size_t)(NUM_GRAPHS * HIDDEN + NUM_GRAPHS) * sizeof(float), stream);
    pool_kernel<<<(N_NODES + 127)/128, 128, 0, stream>>>(H, batch, gsum, gcnt);
    head_kernel<<<NUM_GRAPHS, 128, 0, stream>>>(gsum, gcnt, W1, b1, W_heads, b_heads, out);
}

// Round 9
// 786.156 us; speedup vs baseline: 2.9525x; 1.0905x over previous
//
#include <hip/hip_runtime.h>
#include <hip/hip_bf16.h>
#include <math.h>

// Problem constants (fixed by the reference)
#define N_NODES 50000
#define N_EDGES 800000
#define NODE_DIM 3
#define EDGE_DIM 32
#define HIDDEN 128
#define NUM_GRAPHS 256
#define ZIN (2*HIDDEN + EDGE_DIM)   // 288
#define NPAD 50176                  // 196 * 256 (padded node count for scan)

typedef __attribute__((ext_vector_type(8))) short short8;
typedef __attribute__((ext_vector_type(4))) float f32x4;

// fp32 -> bf16 (RNE), finite inputs
__device__ __forceinline__ unsigned short f2bf(float x) {
    unsigned u = __float_as_uint(x);
    u += 0x7FFFu + ((u >> 16) & 1u);
    return (unsigned short)(u >> 16);
}
// low/high bf16 of a packed uint -> fp32
__device__ __forceinline__ float bf_lo(unsigned u) { return __uint_as_float(u << 16); }
__device__ __forceinline__ float bf_hi(unsigned u) { return __uint_as_float(u & 0xFFFF0000u); }

// ---------------------------------------------------------------------------
// conv1: CGConv on 3-dim features. One thread per edge.
// ---------------------------------------------------------------------------
__global__ __launch_bounds__(256) void conv1_kernel(
    const float* __restrict__ x, const int* __restrict__ ei,
    const float* __restrict__ EA,
    const float* __restrict__ Wf1, const float* __restrict__ bf1,
    const float* __restrict__ Ws1, const float* __restrict__ bs1,
    float* __restrict__ agg0)
{
    __shared__ float WfL[38*3], WsL[38*3], bfL[3], bsL[3];
    if (threadIdx.x < 114) {
        WfL[threadIdx.x] = Wf1[threadIdx.x];
        WsL[threadIdx.x] = Ws1[threadIdx.x];
    }
    if (threadIdx.x < 3) { bfL[threadIdx.x] = bf1[threadIdx.x]; bsL[threadIdx.x] = bs1[threadIdx.x]; }
    __syncthreads();

    int e = blockIdx.x * 256 + threadIdx.x;
    if (e >= N_EDGES) return;
    int s = ei[e];
    int d = ei[N_EDGES + e];

    float z[38];
    z[0] = x[d*3+0]; z[1] = x[d*3+1]; z[2] = x[d*3+2];
    z[3] = x[s*3+0]; z[4] = x[s*3+1]; z[5] = x[s*3+2];
    const float4* ep = (const float4*)(EA + (size_t)e * EDGE_DIM);
    #pragma unroll
    for (int q = 0; q < 8; ++q) {
        float4 v = ep[q];
        z[6+4*q+0] = v.x; z[6+4*q+1] = v.y; z[6+4*q+2] = v.z; z[6+4*q+3] = v.w;
    }
    float f[3], g[3];
    #pragma unroll
    for (int c = 0; c < 3; ++c) { f[c] = bfL[c]; g[c] = bsL[c]; }
    #pragma unroll
    for (int j = 0; j < 38; ++j) {
        #pragma unroll
        for (int c = 0; c < 3; ++c) {
            f[c] += z[j] * WfL[j*3+c];
            g[c] += z[j] * WsL[j*3+c];
        }
    }
    #pragma unroll
    for (int c = 0; c < 3; ++c) {
        float sig = __builtin_amdgcn_rcpf(1.0f + __expf(-f[c]));
        float sp  = fmaxf(g[c], 0.0f) + __logf(1.0f + __expf(-fabsf(g[c])));
        atomicAdd(agg0 + (size_t)d*3 + c, sig * sp);
    }
}

// ---------------------------------------------------------------------------
// proj: H[n][c] = relu(bp[c] + sum_j (x[n][j]+agg0[n][j]) * Wp[j][c])
// ---------------------------------------------------------------------------
__global__ __launch_bounds__(256) void proj_kernel(
    const float* __restrict__ x, const float* __restrict__ agg0,
    const float* __restrict__ Wp, const float* __restrict__ bp,
    float* __restrict__ H)
{
    int idx = blockIdx.x * 256 + threadIdx.x;
    if (idx >= N_NODES * HIDDEN) return;
    int n = idx >> 7, c = idx & 127;
    float h0 = x[n*3+0] + agg0[n*3+0];
    float h1 = x[n*3+1] + agg0[n*3+1];
    float h2 = x[n*3+2] + agg0[n*3+2];
    float v = bp[c] + h0*Wp[0*128+c] + h1*Wp[1*128+c] + h2*Wp[2*128+c];
    H[idx] = fmaxf(v, 0.0f);
}

// ---------------------------------------------------------------------------
// Counting sort of edges by dst: hist -> 2-level exclusive scan -> scatter.
// ---------------------------------------------------------------------------
__global__ __launch_bounds__(256) void hist_kernel(
    const int* __restrict__ ei, int* __restrict__ hist)
{
    int e = blockIdx.x * 256 + threadIdx.x;
    if (e < N_EDGES) atomicAdd(&hist[ei[N_EDGES + e]], 1);
}

__global__ __launch_bounds__(256) void scanA_kernel(
    const int* __restrict__ hist, int* __restrict__ cursor, int* __restrict__ btot)
{
    __shared__ int tmp[256];
    int t = threadIdx.x;
    int i = blockIdx.x * 256 + t;
    int v = hist[i];
    tmp[t] = v;
    __syncthreads();
    #pragma unroll
    for (int off = 1; off < 256; off <<= 1) {
        int y = (t >= off) ? tmp[t - off] : 0;
        __syncthreads();
        if (t >= off) tmp[t] += y;
        __syncthreads();
    }
    cursor[i] = tmp[t] - v;
    if (t == 255) btot[blockIdx.x] = tmp[t];
}

__global__ __launch_bounds__(256) void scanB_kernel(int* __restrict__ btot)
{
    __shared__ int tmp[256];
    int t = threadIdx.x;
    int v = btot[t];
    tmp[t] = v;
    __syncthreads();
    #pragma unroll
    for (int off = 1; off < 256; off <<= 1) {
        int y = (t >= off) ? tmp[t - off] : 0;
        __syncthreads();
        if (t >= off) tmp[t] += y;
        __syncthreads();
    }
    btot[t] = tmp[t] - v;
}

__global__ __launch_bounds__(256) void scanC_kernel(
    int* __restrict__ cursor, const int* __restrict__ btot)
{
    int i = blockIdx.x * 256 + threadIdx.x;
    cursor[i] += btot[blockIdx.x];
}

// Scatter: one int4 store per edge (eid, src, dst, 0) at its sorted slot.
__global__ __launch_bounds__(256) void scatter_kernel(
    const int* __restrict__ ei, int* __restrict__ cursor,
    int4* __restrict__ epack)
{
    int e = blockIdx.x * 256 + threadIdx.x;
    if (e >= N_EDGES) return;
    int s = ei[e];
    int d = ei[N_EDGES + e];
    int p = atomicAdd(&cursor[d], 1);
    epack[p] = make_int4(e, s, d, 0);
}

// ---------------------------------------------------------------------------
// Repack node-path weights into MFMA B-fragment layout (bf16). (Validated.)
// ---------------------------------------------------------------------------
__global__ __launch_bounds__(256) void repack_frag_kernel(
    const float* __restrict__ Wf, const float* __restrict__ Ws,
    unsigned short* __restrict__ Bfrag)
{
    int idx = blockIdx.x * 256 + threadIdx.x;   // 2*32*4*64 = 16384
    if (idx >= 2*32*4*64) return;
    int lane = idx & 63;
    int kc   = (idx >> 6) & 3;
    int nt   = (idx >> 8) & 31;
    int l    = idx >> 13;
    const float* wf  = Wf + (size_t)l * ZIN * HIDDEN;
    const float* wsp = Ws + (size_t)l * ZIN * HIDDEN;
    int n = nt*16 + (lane & 15);
    int half = n >> 8;
    int within = n & 255;
    int cc = within >> 1;
    int t = within & 1;
    const float* W = t ? wsp : wf;
    unsigned short vals[8];
    #pragma unroll
    for (int j = 0; j < 8; ++j) {
        int k = kc*32 + (lane >> 4)*8 + j;
        vals[j] = f2bf(W[(size_t)(half*128 + k)*128 + cc]);
    }
    *(short8*)(Bfrag + (size_t)idx * 8) = *(short8*)vals;
}

// ---------------------------------------------------------------------------
// Repack EDGE-path weights (rows 256..287) into split B-frags (validated).
// ---------------------------------------------------------------------------
__global__ __launch_bounds__(256) void repack_edge_frag_kernel(
    const float* __restrict__ Wf, const float* __restrict__ Ws,
    unsigned short* __restrict__ BE)
{
    int idx = blockIdx.x * 256 + threadIdx.x;   // 2*16*64 = 2048
    if (idx >= 2*16*64) return;
    int lane = idx & 63;
    int nt   = (idx >> 6) & 15;
    int l    = idx >> 10;
    const float* W = ((nt & 8) ? Ws : Wf) + (size_t)l * ZIN * HIDDEN + 256*128;
    int c = (nt & 7)*16 + (lane & 15);
    unsigned short vals[8];
    #pragma unroll
    for (int j = 0; j < 8; ++j) {
        int k = (lane >> 4)*8 + j;
        vals[j] = f2bf(W[(size_t)k*128 + c]);
    }
    *(short8*)(BE + (size_t)idx * 8) = *(short8*)vals;
}

// ---------------------------------------------------------------------------
// Node MFMA GEMM: Pb = bf16((A) @ Wcat + bias), A = H (aggIn==null) or
// relu(H + aggIn) -- the inter-layer update fused into the A-fragment load.
// ---------------------------------------------------------------------------
__global__ __launch_bounds__(256) void gemm_mfma(
    const float* __restrict__ H, const float* __restrict__ aggIn,
    const unsigned short* __restrict__ Bfrag,
    const float* __restrict__ bf, const float* __restrict__ bs,
    unsigned short* __restrict__ Pb)
{
    const int lane = threadIdx.x & 63;
    const int wave = threadIdx.x >> 6;
    const int m    = lane & 15;
    const int quad = lane >> 4;
    const int rowA = blockIdx.y * 64 + wave * 16 + m;   // OOB rows read ws (safe); stores masked
    const int colBase = blockIdx.x * 256;

    const float* hrow = H + (size_t)rowA * 128;
    short8 a[4];
    #pragma unroll
    for (int kc = 0; kc < 4; ++kc) {
        float4 v0 = *(const float4*)(hrow + kc*32 + quad*8);
        float4 v1 = *(const float4*)(hrow + kc*32 + quad*8 + 4);
        if (aggIn) {   // uniform branch: fused relu(H + agg)
            const float* arow = aggIn + (size_t)rowA * 128;
            float4 a0 = *(const float4*)(arow + kc*32 + quad*8);
            float4 a1 = *(const float4*)(arow + kc*32 + quad*8 + 4);
            v0.x = fmaxf(v0.x + a0.x, 0.f); v0.y = fmaxf(v0.y + a0.y, 0.f);
            v0.z = fmaxf(v0.z + a0.z, 0.f); v0.w = fmaxf(v0.w + a0.w, 0.f);
            v1.x = fmaxf(v1.x + a1.x, 0.f); v1.y = fmaxf(v1.y + a1.y, 0.f);
            v1.z = fmaxf(v1.z + a1.z, 0.f); v1.w = fmaxf(v1.w + a1.w, 0.f);
        }
        unsigned short t[8];
        t[0]=f2bf(v0.x); t[1]=f2bf(v0.y); t[2]=f2bf(v0.z); t[3]=f2bf(v0.w);
        t[4]=f2bf(v1.x); t[5]=f2bf(v1.y); t[6]=f2bf(v1.z); t[7]=f2bf(v1.w);
        a[kc] = *(short8*)t;
    }

    f32x4 acc[16];
    #pragma unroll
    for (int nt = 0; nt < 16; ++nt) {
        float bias = 0.0f;
        if (colBase == 0) {
            int col = nt*16 + m;
            bias = (col & 1) ? bs[col >> 1] : bf[col >> 1];
        }
        acc[nt] = (f32x4){bias, bias, bias, bias};
    }

    #pragma unroll
    for (int nt = 0; nt < 16; ++nt) {
        int ntg = (colBase >> 4) + nt;
        const unsigned short* bp = Bfrag + ((size_t)(ntg*4) * 64 + lane) * 8;
        #pragma unroll
        for (int kc = 0; kc < 4; ++kc) {
            short8 b = *(const short8*)(bp + (size_t)kc * 64 * 8);
            acc[nt] = __builtin_amdgcn_mfma_f32_16x16x32_bf16(a[kc], b, acc[nt], 0, 0, 0);
        }
    }

    const int rowC = blockIdx.y * 64 + wave * 16 + quad * 4;
    #pragma unroll
    for (int nt = 0; nt < 16; ++nt) {
        int col = colBase + nt*16 + m;
        #pragma unroll
        for (int r = 0; r < 4; ++r) {
            int row = rowC + r;
            if (row < N_NODES) Pb[(size_t)row * 512 + col] = f2bf(acc[nt][r]);
        }
    }
}

// ---------------------------------------------------------------------------
// Fused edge kernel, v8: dst-sorted + MFMA edge-dot + LDS segmented reduce.
// Changes vs v7: B-frags read DIRECT from global (16 KB, L1-resident) -> LDS
// drops to ~34 KB -> 4 blocks/CU (occupancy 33->50%); edge tuple is one int4;
// single __syncthreads().
// ---------------------------------------------------------------------------
__global__ __launch_bounds__(256) void edge_kernel(
    const unsigned short* __restrict__ Pb, const float* __restrict__ EA,
    const int4* __restrict__ epack,
    const unsigned short* __restrict__ BE,
    float* __restrict__ agg)
{
    __shared__ float msgL[64*132];           // 33.8 KB, stride 132 vs banks
    __shared__ int pdL[64];

    if (threadIdx.x < 64) pdL[threadIdx.x] = epack[blockIdx.x*64 + threadIdx.x].z;

    const int lane = threadIdx.x & 63;
    const int wave = threadIdx.x >> 6;
    const int m    = lane & 15;
    const int quad = lane >> 4;
    const int p0   = blockIdx.x * 64 + wave * 16;   // 800000 % 64 == 0

    // A-frag: EA row of this lane's edge
    int eid = epack[p0 + m].x;
    const float* ea = EA + (size_t)eid * EDGE_DIM + quad*8;
    float4 v0 = *(const float4*)ea;
    float4 v1 = *(const float4*)(ea + 4);
    unsigned short t[8];
    t[0]=f2bf(v0.x); t[1]=f2bf(v0.y); t[2]=f2bf(v0.z); t[3]=f2bf(v0.w);
    t[4]=f2bf(v1.x); t[5]=f2bf(v1.y); t[6]=f2bf(v1.z); t[7]=f2bf(v1.w);
    short8 a = *(short8*)t;

    int dr[4], sr[4];
    #pragma unroll
    for (int r = 0; r < 4; ++r) {
        int4 e = epack[p0 + quad*4 + r];
        sr[r] = e.y; dr[r] = e.z;
    }

    const short8* BEv = (const short8*)BE;   // 16 KB, L1-resident
    const f32x4 zero = (f32x4){0.f, 0.f, 0.f, 0.f};
    #pragma unroll
    for (int nt = 0; nt < 8; ++nt) {
        short8 bF = BEv[nt*64 + lane];
        short8 bS = BEv[(nt+8)*64 + lane];
        f32x4 qf = __builtin_amdgcn_mfma_f32_16x16x32_bf16(a, bF, zero, 0, 0, 0);
        f32x4 qs = __builtin_amdgcn_mfma_f32_16x16x32_bf16(a, bS, zero, 0, 0, 0);
        int c = nt*16 + m;
        #pragma unroll
        for (int r = 0; r < 4; ++r) {
            unsigned pd = *(const unsigned*)(Pb + (size_t)dr[r]*512 + 2*c);
            unsigned ps = *(const unsigned*)(Pb + (size_t)sr[r]*512 + 256 + 2*c);
            float f = bf_lo(pd) + bf_lo(ps) + qf[r];
            float g = bf_hi(pd) + bf_hi(ps) + qs[r];
            float sig = __builtin_amdgcn_rcpf(1.0f + __expf(-f));
            float sp  = fmaxf(g, 0.0f) + __logf(1.0f + __expf(-fabsf(g)));
            msgL[(wave*16 + quad*4 + r)*132 + c] = sig * sp;
        }
    }
    __syncthreads();

    // Segmented reduction: thread -> (channel c2, 32-edge segment)
    const int c2  = threadIdx.x & 127;
    const int seg = threadIdx.x >> 7;
    const int base = seg * 32;
    float acc = 0.0f;
    int cur = pdL[base];
    #pragma unroll 4
    for (int i = 0; i < 32; ++i) {
        int dd = pdL[base + i];
        float v = msgL[(base + i)*132 + c2];
        if (dd != cur) {
            atomicAdd(&agg[(size_t)cur * HIDDEN + c2], acc);
            acc = 0.0f; cur = dd;
        }
        acc += v;
    }
    atomicAdd(&agg[(size_t)cur * HIDDEN + c2], acc);
}

// ---------------------------------------------------------------------------
// Pool with fused double update: h = relu(relu(H+agg1)+agg2); per-graph sums.
// ---------------------------------------------------------------------------
__global__ __launch_bounds__(128) void pool_kernel(
    const float* __restrict__ H, const float* __restrict__ agg1,
    const float* __restrict__ agg2, const int* __restrict__ batch,
    float* __restrict__ gsum, float* __restrict__ gcnt)
{
    const int c = threadIdx.x;
    const int n0 = blockIdx.x * 128;
    float acc = 0.0f;
    int cur = -1;
    for (int i = 0; i < 128; ++i) {
        int n = n0 + i;
        if (n >= N_NODES) break;
        int g = batch[n];
        if (g != cur) {
            if (cur >= 0) atomicAdd(gsum + (size_t)cur * HIDDEN + c, acc);
            cur = g; acc = 0.0f;
        }
        size_t ix = (size_t)n * HIDDEN + c;
        float h = fmaxf(fmaxf(H[ix] + agg1[ix], 0.0f) + agg2[ix], 0.0f);
        acc += h;
    }
    if (cur >= 0) atomicAdd(gsum + (size_t)cur * HIDDEN + c, acc);

    if (c == 0) {
        int curg = -1; float run = 0.0f;
        for (int i = 0; i < 128; ++i) {
            int n = n0 + i;
            if (n >= N_NODES) break;
            int g = batch[n];
            if (g != curg) {
                if (curg >= 0) atomicAdd(gcnt + curg, run);
                curg = g; run = 0.0f;
            }
            run += 1.0f;
        }
        if (curg >= 0) atomicAdd(gcnt + curg, run);
    }
}

// ---------------------------------------------------------------------------
// Final MLP: g = relu((gsum/cnt) @ W1 + b1); out = g @ Wh^T + bh
// ---------------------------------------------------------------------------
__global__ __launch_bounds__(128) void head_kernel(
    const float* __restrict__ gsum, const float* __restrict__ gcnt,
    const float* __restrict__ W1, const float* __restrict__ b1,
    const float* __restrict__ Wh, const float* __restrict__ bh,
    float* __restrict__ out)
{
    __shared__ float gavg[128];
    __shared__ float g1[128];
    const int g = blockIdx.x, c = threadIdx.x;
    float cnt = fmaxf(gcnt[g], 1.0f);
    gavg[c] = gsum[(size_t)g * HIDDEN + c] / cnt;
    __syncthreads();
    float acc = b1[c];
    for (int k = 0; k < 128; ++k) acc += gavg[k] * W1[k*128 + c];
    g1[c] = fmaxf(acc, 0.0f);
    __syncthreads();
    if (c < 5) {
        float o = bh[c];
        for (int k = 0; k < 128; ++k) o += g1[k] * Wh[c*128 + k];
        out[(size_t)g * 5 + c] = o;
    }
}

// ---------------------------------------------------------------------------
// Launch
// ---------------------------------------------------------------------------
extern "C" void kernel_launch(void* const* d_in, const int* in_sizes, int n_in,
                              void* d_out, int out_size, void* d_ws, size_t ws_size,
                              hipStream_t stream) {
    const float* x        = (const float*)d_in[0];
    const int*   ei       = (const int*)  d_in[1];
    const float* EA       = (const float*)d_in[2];
    const int*   batch    = (const int*)  d_in[3];
    const float* Wf1      = (const float*)d_in[4];
    const float* bf1      = (const float*)d_in[5];
    const float* Ws1      = (const float*)d_in[6];
    const float* bs1      = (const float*)d_in[7];
    const float* Wp       = (const float*)d_in[8];
    const float* bp       = (const float*)d_in[9];
    const float* Wf_convs = (const float*)d_in[10];
    const float* bf_convs = (const float*)d_in[11];
    const float* Ws_convs = (const float*)d_in[12];
    const float* bs_convs = (const float*)d_in[13];
    const float* W1       = (const float*)d_in[14];
    const float* b1       = (const float*)d_in[15];
    const float* W_heads  = (const float*)d_in[16];
    const float* b_heads  = (const float*)d_in[17];
    float* out = (float*)d_out;

    float* ws = (float*)d_ws;
    // workspace layout (float units), ~142 MB total
    float* agg0 = ws + 0;                                     // 150016
    float* H    = ws + 150016;                                // 6,400,000
    unsigned short* Pb = (unsigned short*)(ws + 6550016);     // 25.6M ushort
    float* agg1 = ws + 19350016;                              // 6,400,000
    float* agg2 = ws + 25750016;                              // 6,400,000
    unsigned short* Bfrag = (unsigned short*)(ws + 32150016); // 131072 ushort
    unsigned short* BE    = (unsigned short*)(ws + 32215552); // 16384 ushort
    float* gsum = ws + 32223744;                              // 32768
    float* gcnt = ws + 32256512;                              // 256 (+pad)
    int* hist   = (int*)(ws + 32257024);                      // NPAD
    int* cursor = (int*)(ws + 32307200);                      // NPAD
    int* btot   = (int*)(ws + 32357376);                      // 256
    int4* epack = (int4*)(ws + 32357632);                     // 800000 int4

    // ---- edge sort by dst ----
    hipMemsetAsync(hist, 0, (size_t)(2*NPAD + 256) * sizeof(int), stream);
    hist_kernel<<<(N_EDGES + 255)/256, 256, 0, stream>>>(ei, hist);
    scanA_kernel<<<NPAD/256, 256, 0, stream>>>(hist, cursor, btot);
    scanB_kernel<<<1, 256, 0, stream>>>(btot);
    scanC_kernel<<<NPAD/256, 256, 0, stream>>>(cursor, btot);
    scatter_kernel<<<(N_EDGES + 255)/256, 256, 0, stream>>>(ei, cursor, epack);

    // conv1 + proj
    hipMemsetAsync(agg0, 0, (size_t)N_NODES * 3 * sizeof(float), stream);
    conv1_kernel<<<(N_EDGES + 255)/256, 256, 0, stream>>>(x, ei, EA, Wf1, bf1, Ws1, bs1, agg0);
    proj_kernel<<<(N_NODES*HIDDEN + 255)/256, 256, 0, stream>>>(x, agg0, Wp, bp, H);
    // repack weights
    repack_frag_kernel<<<(2*32*4*64 + 255)/256, 256, 0, stream>>>(Wf_convs, Ws_convs, Bfrag);
    repack_edge_frag_kernel<<<(2*16*64 + 255)/256, 256, 0, stream>>>(Wf_convs, Ws_convs, BE);

    dim3 ggrid(2, (N_NODES + 63)/64);
    // ---- layer 0: A = H ----
    gemm_mfma<<<ggrid, 256, 0, stream>>>(H, nullptr, Bfrag, bf_convs, bs_convs, Pb);
    hipMemsetAsync(agg1, 0, (size_t)N_NODES * HIDDEN * sizeof(float), stream);
    edge_kernel<<<N_EDGES/64, 256, 0, stream>>>(Pb, EA, epack, BE, agg1);
    // ---- layer 1: A = relu(H + agg1), fused ----
    gemm_mfma<<<ggrid, 256, 0, stream>>>(H, agg1, Bfrag + (size_t)32*4*64*8,
                                         bf_convs + HIDDEN, bs_convs + HIDDEN, Pb);
    hipMemsetAsync(agg2, 0, (size_t)N_NODES * HIDDEN * sizeof(float), stream);
    edge_kernel<<<N_EDGES/64, 256, 0, stream>>>(Pb, EA, epack, BE + (size_t)16*64*8, agg2);

    // pool (fused relu(relu(H+agg1)+agg2)) + heads
    hipMemsetAsync(gsum, 0, (size_t)(NUM_GRAPHS * HIDDEN + NUM_GRAPHS) * sizeof(float), stream);
    pool_kernel<<<(N_NODES + 127)/128, 128, 0, stream>>>(H, agg1, agg2, batch, gsum, gcnt);
    head_kernel<<<NUM_GRAPHS, 128, 0, stream>>>(gsum, gcnt, W1, b1, W_heads, b_heads, out);
}